// Round 15
// baseline (286.456 us; speedup 1.0000x reference)
//
#include <hip/hip_runtime.h>

#define HW 28
#define NPIX 784   // 28*28
#define NIMG 64
#define NIG  196   // NPIX / 4
#define MAXD2 1459 // d2 <= 2*27^2 = 1458
#define MAXREC 5504  // 783 * 7 worst case

// packed dx/dy (+1, 2 bits each) for {-1,0},{1,0},{0,-1},{0,1},
// {-1,-1},{-1,1},{1,-1},{1,1}; first 4 = 4-connectivity
#define DXPK 41048u
#define DYPK 34949u

// ---------------------------------------------------------------------------
// Kernel 1: grid distance-sort constants via LDS counting sort.
// ---------------------------------------------------------------------------
__global__ void consts_kernel(unsigned short* __restrict__ sortIdx,
                              unsigned short* __restrict__ d2s) {
    __shared__ int cnt[MAXD2];
    __shared__ int d2v[NPIX];
    __shared__ int wtot[4];
    int i = blockIdx.x;
    int tid = threadIdx.x;
    for (int b = tid; b < MAXD2; b += 256) cnt[b] = 0;
    __syncthreads();
    int ii = i / HW, ij = i % HW;
    for (int j = tid; j < NPIX; j += 256) {
        int di = ii - j / HW, dj = ij - j % HW;
        int d = di * di + dj * dj;
        d2v[j] = d;
        atomicAdd(&cnt[d], 1);
    }
    __syncthreads();
    int b0 = tid * 6;
    int lc[6];
    int s0 = 0;
    #pragma unroll
    for (int t = 0; t < 6; ++t) {
        int b = b0 + t;
        lc[t] = (b < MAXD2) ? cnt[b] : 0;
        s0 += lc[t];
    }
    int lane = tid & 63, wv = tid >> 6;
    int v = s0;
    for (int off = 1; off < 64; off <<= 1) {
        int t2 = __shfl_up(v, off, 64);
        if (lane >= off) v += t2;
    }
    if (lane == 63) wtot[wv] = v;
    __syncthreads();
    int wadd = 0;
    for (int w2 = 0; w2 < wv; ++w2) wadd += wtot[w2];
    int run = wadd + v - s0;
    __syncthreads();
    #pragma unroll
    for (int t = 0; t < 6; ++t) {
        int b = b0 + t;
        if (b < MAXD2) { cnt[b] = run; run += lc[t]; }
    }
    __syncthreads();
    for (int j = tid; j < NPIX; j += 256) {
        int d = d2v[j];
        int slot = atomicAdd(&cnt[d], 1);
        sortIdx[i * NPIX + slot] = (unsigned short)j;
        d2s[i * NPIX + slot] = (unsigned short)d;
    }
}

// ---------------------------------------------------------------------------
// Kernel 2: DTM with LDS-staged image row. Block = (m, 4 consecutive i's);
// the image row (3 KB) is loaded coalesced once and the per-lane weight
// gathers become LDS reads. Row sum computed in the same pass (identical
// summation order to the old row_sum kernel). Early exit once cum >= bound2.
// ---------------------------------------------------------------------------
__global__ void dtm_kernel(const float* __restrict__ x,
                           const unsigned short* __restrict__ sortIdx,
                           const unsigned short* __restrict__ d2s,
                           float* __restrict__ F) {
    __shared__ float xs[NPIX];
    __shared__ float red[4];
    int m = blockIdx.x / NIG;
    int ig = blockIdx.x % NIG;
    int tid = threadIdx.x;
    int lane = tid & 63, wv = tid >> 6;
    const float* xr = x + m * NPIX;
    float part = 0.f;
    for (int j = tid; j < NPIX; j += 256) { float vx = xr[j]; xs[j] = vx; part += vx; }
    for (int off = 32; off > 0; off >>= 1) part += __shfl_down(part, off, 64);
    if (lane == 0) red[wv] = part;
    __syncthreads();
    float s = red[0] + red[1] + red[2] + red[3];

    int i = ig * 4 + wv;                    // always < NPIX
    float bound1 = 0.05f * s, bound2 = 0.2f * s;
    const unsigned short* si = sortIdx + (size_t)i * NPIX;
    const unsigned short* dr = d2s + (size_t)i * NPIX;
    float carry = 0.f, acc1 = 0.f, acc2 = 0.f;
    for (int c = 0; c < 4; ++c) {           // 4*256 = 1024 >= 784
        int j0 = c * 256 + lane * 4;        // 784 % 4 == 0: all-or-nothing
        float w0 = 0.f, w1 = 0.f, w2 = 0.f, w3 = 0.f;
        float d0 = 0.f, d1 = 0.f, d2 = 0.f, d3 = 0.f;
        if (j0 < NPIX) {
            ushort4 sv = *(const ushort4*)(si + j0);
            ushort4 dv = *(const ushort4*)(dr + j0);
            w0 = xs[sv.x]; w1 = xs[sv.y]; w2 = xs[sv.z]; w3 = xs[sv.w];
            d0 = (float)dv.x; d1 = (float)dv.y; d2 = (float)dv.z; d3 = (float)dv.w;
        }
        float ps = w0 + w1 + w2 + w3;
        float v = ps;
        for (int off = 1; off < 64; off <<= 1) {
            float t = __shfl_up(v, off, 64);
            if (lane >= off) v += t;
        }
        float c0 = carry + v - ps;          // exclusive prefix before elem0
        float c1 = c0 + w0, c2 = c1 + w1, c3 = c2 + w2;
        acc1 += fminf(fmaxf(bound1 - c0, 0.f), w0) * d0
              + fminf(fmaxf(bound1 - c1, 0.f), w1) * d1
              + fminf(fmaxf(bound1 - c2, 0.f), w2) * d2
              + fminf(fmaxf(bound1 - c3, 0.f), w3) * d3;
        acc2 += fminf(fmaxf(bound2 - c0, 0.f), w0) * d0
              + fminf(fmaxf(bound2 - c1, 0.f), w1) * d1
              + fminf(fmaxf(bound2 - c2, 0.f), w2) * d2
              + fminf(fmaxf(bound2 - c3, 0.f), w3) * d3;
        carry += __shfl(v, 63, 64);
        if (carry >= bound2) break;         // wave-uniform: later eff == 0
    }
    for (int off = 32; off > 0; off >>= 1) {
        acc1 += __shfl_down(acc1, off, 64);
        acc2 += __shfl_down(acc2, off, 64);
    }
    if (lane == 0) {
        F[0 * NIMG * NPIX + m * NPIX + i] = sqrtf(acc1 / bound1);
        F[1 * NIMG * NPIX + m * NPIX + i] = sqrtf(acc2 / bound2);
    }
}

// ---------------------------------------------------------------------------
// Kernel 3: fused RANK + UF (basin decomposition) + LANDSCAPE + (last block)
// MLP. One 256-thread block per task. P4 reads a single packed (pos,bas)
// word per neighbor (ukey reused after rank). Last block (device-scope
// atomic + fences per G16) runs the 64-image MLP head.
// ---------------------------------------------------------------------------
template<int NN>   // NN = 4 (dir 0) or 8 (dir 1)
__device__ int uf_basin_run(const int* posA, const int* ordA,
                            int* bas, unsigned int* pb, int* comp,
                            int* recs, int* pairsI,
                            int2* mergeLDS, int* shInts, int* wtot4) {
    const int tid = threadIdx.x;
    const int lane = tid & 63, wv = tid >> 6;

    // ---- P2: steepest-descent forest ----
    for (int s = tid; s < NPIX; s += 256) {
        int si = s / HW, sj = s % HW;
        int bestPos = posA[s], best = s;
        #pragma unroll
        for (int o = 0; o < NN; ++o) {
            int dx = ((DXPK >> (2 * o)) & 3) - 1;
            int dy = ((DYPK >> (2 * o)) & 3) - 1;
            int ui = si + dx, uj = sj + dy;
            if ((unsigned)ui < (unsigned)HW && (unsigned)uj < (unsigned)HW) {
                int u = ui * HW + uj;
                int pu = posA[u];
                if (pu < bestPos) { bestPos = pu; best = u; }
            }
        }
        bas[s] = best;
    }
    __syncthreads();

    // ---- P3: pointer jumping with convergence early-exit ----
    for (int it = 0; it < 10; ++it) {
        int changed = 0;
        for (int s = tid; s < NPIX; s += 256) {
            int b = bas[s];
            int bb = bas[b];
            if (bb != b) { bas[s] = bb; changed = 1; }
        }
        if (__syncthreads_count(changed) == 0) break;
    }

    // ---- pack (pos<<10 | bas) for single-gather P4 ----
    for (int s = tid; s < NPIX; s += 256)
        pb[s] = ((unsigned)posA[s] << 10) | (unsigned)bas[s];
    __syncthreads();

    // ---- P4: candidate records in rank order, block-scan compaction ----
    int nrec = 0;
    for (int c = 0; c < 4; ++c) {
        int r = c * 256 + tid;
        int cnt = 0;
        int myr[NN - 1];
        int got[NN - 1];
        #pragma unroll
        for (int t = 0; t < NN - 1; ++t) { got[t] = -1; myr[t] = 0; }
        if (r > 0 && r < NPIX) {
            int v = ordA[r];
            int vi = v / HW, vj = v % HW;
            int pivot = (int)(pb[v] & 1023u);
            #pragma unroll
            for (int o = 0; o < NN; ++o) {
                int dx = ((DXPK >> (2 * o)) & 3) - 1;
                int dy = ((DYPK >> (2 * o)) & 3) - 1;
                int ui = vi + dx, uj = vj + dy;
                if ((unsigned)ui < (unsigned)HW && (unsigned)uj < (unsigned)HW) {
                    int u = ui * HW + uj;
                    unsigned e = pb[u];
                    if ((int)(e >> 10) < r) {
                        int b = (int)(e & 1023u);
                        bool dup = (b == pivot);
                        #pragma unroll
                        for (int t = 0; t < NN - 1; ++t) dup = dup || (got[t] == b);
                        if (!dup) {
                            #pragma unroll
                            for (int t = 0; t < NN - 1; ++t)
                                if (t == cnt) { got[t] = b; myr[t] = (v << 20) | (pivot << 10) | b; }
                            cnt++;
                        }
                    }
                }
            }
        }
        // block-wide exclusive prefix of cnt
        int p = cnt;
        for (int off = 1; off < 64; off <<= 1) {
            int t2 = __shfl_up(p, off, 64);
            if (lane >= off) p += t2;
        }
        if (lane == 63) wtot4[wv] = p;
        __syncthreads();
        int wadd = 0;
        for (int w2 = 0; w2 < wv; ++w2) wadd += wtot4[w2];
        int tot = wtot4[0] + wtot4[1] + wtot4[2] + wtot4[3];
        int excl = wadd + p - cnt;
        #pragma unroll
        for (int t = 0; t < NN - 1; ++t)
            if (t < cnt) recs[nrec + excl + t] = myr[t];
        nrec += tot;
        __syncthreads();
    }

    // ---- P5: ballot-driven serial UF (wave 0), block-wide flatten ----
    int k = 0;
    for (int base = 0; base < nrec; base += 64) {
        int nrem = 0;
        if (wv == 0) {
            int idx = base + lane;
            int rec = (idx < nrec) ? recs[idx] : 0;
            int pa = (rec >> 10) & 1023, pbn = rec & 1023;
            int ka = 0, kb = 0;
            if (idx < nrec) { ka = comp[pa]; kb = comp[pbn]; }
            for (;;) {
                unsigned long long d = __ballot(ka != kb);
                if (d == 0ull) break;
                int i = (int)__ffsll((long long)d) - 1;   // lowest lane = lowest rank
                int sA = __builtin_amdgcn_readlane(ka, i);
                int sB = __builtin_amdgcn_readlane(kb, i);
                int w = min(sA, sB), l = max(sA, sB);     // uniform scalars
                int sv = __builtin_amdgcn_readlane(rec, i) >> 20;
                if (lane == 0) {
                    pairsI[k] = (l & 1023) | (sv << 10);
                    mergeLDS[nrem] = make_int2(l, w);
                }
                k++;
                ka = (ka == l) ? w : ka;
                kb = (kb == l) ? w : kb;
                nrem++;
                if (nrem == 63) {              // overflow guard (rare): wave-0 flatten
                    for (int s = lane; s < NPIX; s += 64) {
                        int cv = comp[s], c0 = cv;
                        for (int e = 0; e < nrem; ++e) {
                            int2 me = mergeLDS[e];
                            cv = (cv == me.x) ? me.y : cv;
                        }
                        if (cv != c0) comp[s] = cv;
                    }
                    if (idx < nrec) { ka = comp[pa]; kb = comp[pbn]; }
                    nrem = 0;
                }
            }
            if (lane == 0) shInts[0] = nrem;
        }
        __syncthreads();
        int nr = shInts[0];
        if (nr > 0) {                          // flatten with all 256 threads
            for (int s = tid; s < NPIX; s += 256) {
                int cv = comp[s], c0 = cv;
                for (int e = 0; e < nr; ++e) {
                    int2 me = mergeLDS[e];
                    cv = (cv == me.x) ? me.y : cv;
                }
                if (cv != c0) comp[s] = cv;
            }
        }
        __syncthreads();
    }
    if (tid == 0) shInts[1] = k;
    __syncthreads();
    return shInts[1];
}

__global__ void __launch_bounds__(256) uf_land_kernel(const float* __restrict__ F,
                                                      float* __restrict__ LAM1,
                                                      float* __restrict__ LAM2,
                                                      const float* __restrict__ w1,
                                                      const float* __restrict__ b1,
                                                      const float* __restrict__ w2,
                                                      const float* __restrict__ b2,
                                                      const float* __restrict__ wf,
                                                      const float* __restrict__ bf,
                                                      float* __restrict__ out,
                                                      int* __restrict__ cnt) {
    __shared__ int posA[NPIX], ordA[NPIX], bas[NPIX], comp[NPIX], pairsI[NPIX];
    __shared__ unsigned int ukey[NPIX];   // rank keys, then packed (pos,bas)
    __shared__ float fv[NPIX];
    __shared__ float2 pairs[NPIX];
    __shared__ int recs[MAXREC];
    __shared__ int2 mergeLDS[64];
    __shared__ int shInts[3];
    __shared__ int wtot4[4];
    __shared__ float xc[4][64];
    int tid = threadIdx.x;
    int task = blockIdx.x;
    int feat = task >> 7;
    int dir = (task >> 6) & 1;
    int m = task & 63;
    const float* fr = F + feat * NIMG * NPIX + m * NPIX;

    // load values + dir-adjusted sortable keys (values >= 0: bits monotone)
    for (int j = tid; j < NPIX; j += 256) {
        float f = fr[j];
        fv[j] = f;
        unsigned int b = __float_as_uint(f);
        ukey[j] = dir ? ~b : b;
    }
    __syncthreads();

    // ---- fused rank (register-blocked, b128 LDS reads, u64 packed keys) ----
    {
        unsigned long long pki[4];
        int rank[4] = {0, 0, 0, 0};
        bool val[4];
        #pragma unroll
        for (int r = 0; r < 4; ++r) {
            int i = tid + 256 * r;
            val[r] = (i < NPIX);
            pki[r] = val[r] ? (((unsigned long long)ukey[i] << 10) | (unsigned)i) : 0ull;
        }
        const uint4* k4 = (const uint4*)ukey;
        for (int c = 0; c < NPIX / 4; ++c) {
            uint4 kv = k4[c];
            unsigned q = 4u * c;
            unsigned long long p0 = ((unsigned long long)kv.x << 10) | q;
            unsigned long long p1 = ((unsigned long long)kv.y << 10) | (q + 1);
            unsigned long long p2 = ((unsigned long long)kv.z << 10) | (q + 2);
            unsigned long long p3 = ((unsigned long long)kv.w << 10) | (q + 3);
            #pragma unroll
            for (int r = 0; r < 4; ++r) {
                rank[r] += (int)(p0 < pki[r]) + (int)(p1 < pki[r])
                         + (int)(p2 < pki[r]) + (int)(p3 < pki[r]);
            }
        }
        #pragma unroll
        for (int r = 0; r < 4; ++r) {
            if (val[r]) {
                int i = tid + 256 * r;
                posA[i] = rank[r];
                ordA[rank[r]] = i;
            }
        }
    }
    __syncthreads();
    for (int s = tid; s < NPIX; s += 256) comp[s] = (posA[s] << 10) | s;
    // (comp init needs no barrier before P2: P2 reads only posA)

    int k;
    if (dir == 0) k = uf_basin_run<4>(posA, ordA, bas, ukey, comp, recs, pairsI,
                                      mergeLDS, shInts, wtot4);
    else          k = uf_basin_run<8>(posA, ordA, bas, ukey, comp, recs, pairsI,
                                      mergeLDS, shInts, wtot4);

    // convert packed pairs to (b, d) float values (dir 1 stores swapped)
    for (int s = tid; s < k; s += 256) {
        int p = pairsI[s];
        float fb = fv[p & 1023], fd = fv[p >> 10];
        pairs[s] = dir ? make_float2(fd, fb) : make_float2(fb, fd);
    }
    __syncthreads();

    // ---- fused landscape: top-3 tents over the k real pairs ----
    if (tid < 32) {
        int t = tid;
        float start = (feat == 0) ? 0.f : 1.f;
        float end   = (feat == 0) ? 7.f : 8.f;
        float tv = start + (end - start) * ((float)t / 31.f);
        float v0 = 0.f, v1 = 0.f, v2 = 0.f;
        for (int p = 0; p < k; ++p) {
            float2 bd = pairs[p];
            float tent = fmaxf(fminf(tv - bd.x, bd.y - tv), 0.f);
            if (tent > v0)      { v2 = v1; v1 = v0; v0 = tent; }
            else if (tent > v1) { v2 = v1; v1 = tent; }
            else if (tent > v2) { v2 = tent; }
        }
        if (feat == 0) {
            float* lam = LAM1 + m * 128 + dir * 64;
            lam[0 * 32 + t] = v0;
            lam[1 * 32 + t] = v1;
        } else {
            float* lam = LAM2 + m * 192 + dir * 96;
            lam[0 * 32 + t] = v0;
            lam[1 * 32 + t] = v1;
            lam[2 * 32 + t] = v2;
        }
    }

    // ---- last-block MLP head (device-scope release/acquire per G16) ----
    __threadfence();                       // release LAM stores (wave 0 wrote them)
    __syncthreads();
    if (tid == 0) shInts[2] = (atomicAdd(cnt, 1) == gridDim.x - 1);
    __syncthreads();
    if (shInts[2]) {
        __threadfence();                   // acquire: see all blocks' LAM
        int g = tid >> 6, n = tid & 63;
        for (int pass = 0; pass < 16; ++pass) {
            int mm = pass * 4 + g;
            float acc;
            if (n < 32) {
                acc = b1[n];
                const float* l = LAM1 + mm * 128;
                for (int c = 0; c < 128; ++c) acc += w1[n * 128 + c] * l[c];
            } else {
                int n2 = n - 32;
                acc = b2[n2];
                const float* l = LAM2 + mm * 192;
                for (int c = 0; c < 192; ++c) acc += w2[n2 * 192 + c] * l[c];
            }
            xc[g][n] = fmaxf(acc, 0.f);
            __syncthreads();
            if (n < 10) {
                float o = bf[n];
                for (int c = 0; c < 64; ++c) o += wf[n * 64 + c] * xc[g][c];
                out[mm * 10 + n] = o;
            }
            __syncthreads();
        }
    }
}

extern "C" void kernel_launch(void* const* d_in, const int* in_sizes, int n_in,
                              void* d_out, int out_size, void* d_ws, size_t ws_size,
                              hipStream_t stream) {
    const float* x  = (const float*)d_in[0];
    const float* w1 = (const float*)d_in[1];
    const float* b1 = (const float*)d_in[2];
    const float* w2 = (const float*)d_in[3];
    const float* b2 = (const float*)d_in[4];
    const float* wf = (const float*)d_in[5];
    const float* bf = (const float*)d_in[6];
    float* out = (float*)d_out;

    char* ws = (char*)d_ws;
    size_t off = 0;
    unsigned short* SORT = (unsigned short*)(ws + off); off += (size_t)NPIX * NPIX * 2;
    unsigned short* D2S  = (unsigned short*)(ws + off); off += (size_t)NPIX * NPIX * 2;
    float* F    = (float*)(ws + off); off += (size_t)2 * NIMG * NPIX * 4;
    float* LAM1 = (float*)(ws + off); off += (size_t)NIMG * 128 * 4;
    float* LAM2 = (float*)(ws + off); off += (size_t)NIMG * 192 * 4;
    int* CNT    = (int*)(ws + off);   off += 256;

    hipMemsetAsync(CNT, 0, 4, stream);
    consts_kernel<<<NPIX, 256, 0, stream>>>(SORT, D2S);
    dtm_kernel<<<NIMG * NIG, 256, 0, stream>>>(x, SORT, D2S, F);
    uf_land_kernel<<<256, 256, 0, stream>>>(F, LAM1, LAM2,
                                            w1, b1, w2, b2, wf, bf, out, CNT);
}

// Round 16
// 152.988 us; speedup vs baseline: 1.8724x; 1.8724x over previous
//
#include <hip/hip_runtime.h>

#define HW 28
#define NPIX 784   // 28*28
#define NIMG 64
#define NIG  196   // NPIX / 4
#define MAXD2 1459 // d2 <= 2*27^2 = 1458
#define MAXREC 5504  // 783 * 7 worst case

// packed dx/dy (+1, 2 bits each) for {-1,0},{1,0},{0,-1},{0,1},
// {-1,-1},{-1,1},{1,-1},{1,1}; first 4 = 4-connectivity
#define DXPK 41048u
#define DYPK 34949u

// ---------------------------------------------------------------------------
// Kernel 1: grid distance-sort constants via LDS counting sort.
// ---------------------------------------------------------------------------
__global__ void consts_kernel(unsigned short* __restrict__ sortIdx,
                              unsigned short* __restrict__ d2s) {
    __shared__ int cnt[MAXD2];
    __shared__ int d2v[NPIX];
    __shared__ int wtot[4];
    int i = blockIdx.x;
    int tid = threadIdx.x;
    for (int b = tid; b < MAXD2; b += 256) cnt[b] = 0;
    __syncthreads();
    int ii = i / HW, ij = i % HW;
    for (int j = tid; j < NPIX; j += 256) {
        int di = ii - j / HW, dj = ij - j % HW;
        int d = di * di + dj * dj;
        d2v[j] = d;
        atomicAdd(&cnt[d], 1);
    }
    __syncthreads();
    int b0 = tid * 6;
    int lc[6];
    int s0 = 0;
    #pragma unroll
    for (int t = 0; t < 6; ++t) {
        int b = b0 + t;
        lc[t] = (b < MAXD2) ? cnt[b] : 0;
        s0 += lc[t];
    }
    int lane = tid & 63, wv = tid >> 6;
    int v = s0;
    for (int off = 1; off < 64; off <<= 1) {
        int t2 = __shfl_up(v, off, 64);
        if (lane >= off) v += t2;
    }
    if (lane == 63) wtot[wv] = v;
    __syncthreads();
    int wadd = 0;
    for (int w2 = 0; w2 < wv; ++w2) wadd += wtot[w2];
    int run = wadd + v - s0;
    __syncthreads();
    #pragma unroll
    for (int t = 0; t < 6; ++t) {
        int b = b0 + t;
        if (b < MAXD2) { cnt[b] = run; run += lc[t]; }
    }
    __syncthreads();
    for (int j = tid; j < NPIX; j += 256) {
        int d = d2v[j];
        int slot = atomicAdd(&cnt[d], 1);
        sortIdx[i * NPIX + slot] = (unsigned short)j;
        d2s[i * NPIX + slot] = (unsigned short)d;
    }
}

// ---------------------------------------------------------------------------
// Kernel 2: DTM with LDS-staged image row. Block = (m, 4 consecutive i's);
// image row loaded coalesced once; row sum computed in the same pass
// (identical summation order to the old row_sum kernel). Early exit once
// cum >= bound2 (later eff terms exactly 0).
// ---------------------------------------------------------------------------
__global__ void dtm_kernel(const float* __restrict__ x,
                           const unsigned short* __restrict__ sortIdx,
                           const unsigned short* __restrict__ d2s,
                           float* __restrict__ F) {
    __shared__ float xs[NPIX];
    __shared__ float red[4];
    int m = blockIdx.x / NIG;
    int ig = blockIdx.x % NIG;
    int tid = threadIdx.x;
    int lane = tid & 63, wv = tid >> 6;
    const float* xr = x + m * NPIX;
    float part = 0.f;
    for (int j = tid; j < NPIX; j += 256) { float vx = xr[j]; xs[j] = vx; part += vx; }
    for (int off = 32; off > 0; off >>= 1) part += __shfl_down(part, off, 64);
    if (lane == 0) red[wv] = part;
    __syncthreads();
    float s = red[0] + red[1] + red[2] + red[3];

    int i = ig * 4 + wv;                    // always < NPIX
    float bound1 = 0.05f * s, bound2 = 0.2f * s;
    const unsigned short* si = sortIdx + (size_t)i * NPIX;
    const unsigned short* dr = d2s + (size_t)i * NPIX;
    float carry = 0.f, acc1 = 0.f, acc2 = 0.f;
    for (int c = 0; c < 4; ++c) {           // 4*256 = 1024 >= 784
        int j0 = c * 256 + lane * 4;        // 784 % 4 == 0: all-or-nothing
        float w0 = 0.f, w1 = 0.f, w2 = 0.f, w3 = 0.f;
        float d0 = 0.f, d1 = 0.f, d2 = 0.f, d3 = 0.f;
        if (j0 < NPIX) {
            ushort4 sv = *(const ushort4*)(si + j0);
            ushort4 dv = *(const ushort4*)(dr + j0);
            w0 = xs[sv.x]; w1 = xs[sv.y]; w2 = xs[sv.z]; w3 = xs[sv.w];
            d0 = (float)dv.x; d1 = (float)dv.y; d2 = (float)dv.z; d3 = (float)dv.w;
        }
        float ps = w0 + w1 + w2 + w3;
        float v = ps;
        for (int off = 1; off < 64; off <<= 1) {
            float t = __shfl_up(v, off, 64);
            if (lane >= off) v += t;
        }
        float c0 = carry + v - ps;          // exclusive prefix before elem0
        float c1 = c0 + w0, c2 = c1 + w1, c3 = c2 + w2;
        acc1 += fminf(fmaxf(bound1 - c0, 0.f), w0) * d0
              + fminf(fmaxf(bound1 - c1, 0.f), w1) * d1
              + fminf(fmaxf(bound1 - c2, 0.f), w2) * d2
              + fminf(fmaxf(bound1 - c3, 0.f), w3) * d3;
        acc2 += fminf(fmaxf(bound2 - c0, 0.f), w0) * d0
              + fminf(fmaxf(bound2 - c1, 0.f), w1) * d1
              + fminf(fmaxf(bound2 - c2, 0.f), w2) * d2
              + fminf(fmaxf(bound2 - c3, 0.f), w3) * d3;
        carry += __shfl(v, 63, 64);
        if (carry >= bound2) break;         // wave-uniform: later eff == 0
    }
    for (int off = 32; off > 0; off >>= 1) {
        acc1 += __shfl_down(acc1, off, 64);
        acc2 += __shfl_down(acc2, off, 64);
    }
    if (lane == 0) {
        F[0 * NIMG * NPIX + m * NPIX + i] = sqrtf(acc1 / bound1);
        F[1 * NIMG * NPIX + m * NPIX + i] = sqrtf(acc2 / bound2);
    }
}

// ---------------------------------------------------------------------------
// Kernel 3: fused RANK + UF (basin decomposition) + LANDSCAPE.
// One 256-thread block per task. P4 reads a single packed (pos,bas) word
// per neighbor (ukey reused after rank). NO device-scope fences (round-15
// lesson: 256-block threadfence + last-block MLP cost ~150 µs; the kernel
// boundary IS the cheap device-wide barrier).
// ---------------------------------------------------------------------------
template<int NN>   // NN = 4 (dir 0) or 8 (dir 1)
__device__ int uf_basin_run(const int* posA, const int* ordA,
                            int* bas, unsigned int* pb, int* comp,
                            int* recs, int* pairsI,
                            int2* mergeLDS, int* shInts, int* wtot4) {
    const int tid = threadIdx.x;
    const int lane = tid & 63, wv = tid >> 6;

    // ---- P2: steepest-descent forest ----
    for (int s = tid; s < NPIX; s += 256) {
        int si = s / HW, sj = s % HW;
        int bestPos = posA[s], best = s;
        #pragma unroll
        for (int o = 0; o < NN; ++o) {
            int dx = ((DXPK >> (2 * o)) & 3) - 1;
            int dy = ((DYPK >> (2 * o)) & 3) - 1;
            int ui = si + dx, uj = sj + dy;
            if ((unsigned)ui < (unsigned)HW && (unsigned)uj < (unsigned)HW) {
                int u = ui * HW + uj;
                int pu = posA[u];
                if (pu < bestPos) { bestPos = pu; best = u; }
            }
        }
        bas[s] = best;
    }
    __syncthreads();

    // ---- P3: pointer jumping with convergence early-exit ----
    for (int it = 0; it < 10; ++it) {
        int changed = 0;
        for (int s = tid; s < NPIX; s += 256) {
            int b = bas[s];
            int bb = bas[b];
            if (bb != b) { bas[s] = bb; changed = 1; }
        }
        if (__syncthreads_count(changed) == 0) break;
    }

    // ---- pack (pos<<10 | bas) for single-gather P4 ----
    for (int s = tid; s < NPIX; s += 256)
        pb[s] = ((unsigned)posA[s] << 10) | (unsigned)bas[s];
    __syncthreads();

    // ---- P4: candidate records in rank order, block-scan compaction ----
    int nrec = 0;
    for (int c = 0; c < 4; ++c) {
        int r = c * 256 + tid;
        int cnt = 0;
        int myr[NN - 1];
        int got[NN - 1];
        #pragma unroll
        for (int t = 0; t < NN - 1; ++t) { got[t] = -1; myr[t] = 0; }
        if (r > 0 && r < NPIX) {
            int v = ordA[r];
            int vi = v / HW, vj = v % HW;
            int pivot = (int)(pb[v] & 1023u);
            #pragma unroll
            for (int o = 0; o < NN; ++o) {
                int dx = ((DXPK >> (2 * o)) & 3) - 1;
                int dy = ((DYPK >> (2 * o)) & 3) - 1;
                int ui = vi + dx, uj = vj + dy;
                if ((unsigned)ui < (unsigned)HW && (unsigned)uj < (unsigned)HW) {
                    int u = ui * HW + uj;
                    unsigned e = pb[u];
                    if ((int)(e >> 10) < r) {
                        int b = (int)(e & 1023u);
                        bool dup = (b == pivot);
                        #pragma unroll
                        for (int t = 0; t < NN - 1; ++t) dup = dup || (got[t] == b);
                        if (!dup) {
                            #pragma unroll
                            for (int t = 0; t < NN - 1; ++t)
                                if (t == cnt) { got[t] = b; myr[t] = (v << 20) | (pivot << 10) | b; }
                            cnt++;
                        }
                    }
                }
            }
        }
        // block-wide exclusive prefix of cnt
        int p = cnt;
        for (int off = 1; off < 64; off <<= 1) {
            int t2 = __shfl_up(p, off, 64);
            if (lane >= off) p += t2;
        }
        if (lane == 63) wtot4[wv] = p;
        __syncthreads();
        int wadd = 0;
        for (int w2 = 0; w2 < wv; ++w2) wadd += wtot4[w2];
        int tot = wtot4[0] + wtot4[1] + wtot4[2] + wtot4[3];
        int excl = wadd + p - cnt;
        #pragma unroll
        for (int t = 0; t < NN - 1; ++t)
            if (t < cnt) recs[nrec + excl + t] = myr[t];
        nrec += tot;
        __syncthreads();
    }

    // ---- P5: ballot-driven serial UF (wave 0), block-wide flatten ----
    int k = 0;
    for (int base = 0; base < nrec; base += 64) {
        int nrem = 0;
        if (wv == 0) {
            int idx = base + lane;
            int rec = (idx < nrec) ? recs[idx] : 0;
            int pa = (rec >> 10) & 1023, pbn = rec & 1023;
            int ka = 0, kb = 0;
            if (idx < nrec) { ka = comp[pa]; kb = comp[pbn]; }
            for (;;) {
                unsigned long long d = __ballot(ka != kb);
                if (d == 0ull) break;
                int i = (int)__ffsll((long long)d) - 1;   // lowest lane = lowest rank
                int sA = __builtin_amdgcn_readlane(ka, i);
                int sB = __builtin_amdgcn_readlane(kb, i);
                int w = min(sA, sB), l = max(sA, sB);     // uniform scalars
                int sv = __builtin_amdgcn_readlane(rec, i) >> 20;
                if (lane == 0) {
                    pairsI[k] = (l & 1023) | (sv << 10);
                    mergeLDS[nrem] = make_int2(l, w);
                }
                k++;
                ka = (ka == l) ? w : ka;
                kb = (kb == l) ? w : kb;
                nrem++;
                if (nrem == 63) {              // overflow guard (rare): wave-0 flatten
                    for (int s = lane; s < NPIX; s += 64) {
                        int cv = comp[s], c0 = cv;
                        for (int e = 0; e < nrem; ++e) {
                            int2 me = mergeLDS[e];
                            cv = (cv == me.x) ? me.y : cv;
                        }
                        if (cv != c0) comp[s] = cv;
                    }
                    if (idx < nrec) { ka = comp[pa]; kb = comp[pbn]; }
                    nrem = 0;
                }
            }
            if (lane == 0) shInts[0] = nrem;
        }
        __syncthreads();
        int nr = shInts[0];
        if (nr > 0) {                          // flatten with all 256 threads
            for (int s = tid; s < NPIX; s += 256) {
                int cv = comp[s], c0 = cv;
                for (int e = 0; e < nr; ++e) {
                    int2 me = mergeLDS[e];
                    cv = (cv == me.x) ? me.y : cv;
                }
                if (cv != c0) comp[s] = cv;
            }
        }
        __syncthreads();
    }
    if (tid == 0) shInts[1] = k;
    __syncthreads();
    return shInts[1];
}

__global__ void __launch_bounds__(256) uf_land_kernel(const float* __restrict__ F,
                                                      float* __restrict__ LAM1,
                                                      float* __restrict__ LAM2) {
    __shared__ int posA[NPIX], ordA[NPIX], bas[NPIX], comp[NPIX], pairsI[NPIX];
    __shared__ unsigned int ukey[NPIX];   // rank keys, then packed (pos,bas)
    __shared__ float fv[NPIX];
    __shared__ float2 pairs[NPIX];
    __shared__ int recs[MAXREC];
    __shared__ int2 mergeLDS[64];
    __shared__ int shInts[2];
    __shared__ int wtot4[4];
    int tid = threadIdx.x;
    int task = blockIdx.x;
    int feat = task >> 7;
    int dir = (task >> 6) & 1;
    int m = task & 63;
    const float* fr = F + feat * NIMG * NPIX + m * NPIX;

    // load values + dir-adjusted sortable keys (values >= 0: bits monotone)
    for (int j = tid; j < NPIX; j += 256) {
        float f = fr[j];
        fv[j] = f;
        unsigned int b = __float_as_uint(f);
        ukey[j] = dir ? ~b : b;
    }
    __syncthreads();

    // ---- fused rank (register-blocked, b128 LDS reads, u64 packed keys) ----
    {
        unsigned long long pki[4];
        int rank[4] = {0, 0, 0, 0};
        bool val[4];
        #pragma unroll
        for (int r = 0; r < 4; ++r) {
            int i = tid + 256 * r;
            val[r] = (i < NPIX);
            pki[r] = val[r] ? (((unsigned long long)ukey[i] << 10) | (unsigned)i) : 0ull;
        }
        const uint4* k4 = (const uint4*)ukey;
        for (int c = 0; c < NPIX / 4; ++c) {
            uint4 kv = k4[c];
            unsigned q = 4u * c;
            unsigned long long p0 = ((unsigned long long)kv.x << 10) | q;
            unsigned long long p1 = ((unsigned long long)kv.y << 10) | (q + 1);
            unsigned long long p2 = ((unsigned long long)kv.z << 10) | (q + 2);
            unsigned long long p3 = ((unsigned long long)kv.w << 10) | (q + 3);
            #pragma unroll
            for (int r = 0; r < 4; ++r) {
                rank[r] += (int)(p0 < pki[r]) + (int)(p1 < pki[r])
                         + (int)(p2 < pki[r]) + (int)(p3 < pki[r]);
            }
        }
        #pragma unroll
        for (int r = 0; r < 4; ++r) {
            if (val[r]) {
                int i = tid + 256 * r;
                posA[i] = rank[r];
                ordA[rank[r]] = i;
            }
        }
    }
    __syncthreads();
    for (int s = tid; s < NPIX; s += 256) comp[s] = (posA[s] << 10) | s;
    // (comp init needs no barrier before P2: P2 reads only posA)

    int k;
    if (dir == 0) k = uf_basin_run<4>(posA, ordA, bas, ukey, comp, recs, pairsI,
                                      mergeLDS, shInts, wtot4);
    else          k = uf_basin_run<8>(posA, ordA, bas, ukey, comp, recs, pairsI,
                                      mergeLDS, shInts, wtot4);

    // convert packed pairs to (b, d) float values (dir 1 stores swapped)
    for (int s = tid; s < k; s += 256) {
        int p = pairsI[s];
        float fb = fv[p & 1023], fd = fv[p >> 10];
        pairs[s] = dir ? make_float2(fd, fb) : make_float2(fb, fd);
    }
    __syncthreads();

    // ---- fused landscape: top-3 tents over the k real pairs ----
    if (tid < 32) {
        int t = tid;
        float start = (feat == 0) ? 0.f : 1.f;
        float end   = (feat == 0) ? 7.f : 8.f;
        float tv = start + (end - start) * ((float)t / 31.f);
        float v0 = 0.f, v1 = 0.f, v2 = 0.f;
        for (int p = 0; p < k; ++p) {
            float2 bd = pairs[p];
            float tent = fmaxf(fminf(tv - bd.x, bd.y - tv), 0.f);
            if (tent > v0)      { v2 = v1; v1 = v0; v0 = tent; }
            else if (tent > v1) { v2 = v1; v1 = tent; }
            else if (tent > v2) { v2 = tent; }
        }
        if (feat == 0) {
            float* lam = LAM1 + m * 128 + dir * 64;
            lam[0 * 32 + t] = v0;
            lam[1 * 32 + t] = v1;
        } else {
            float* lam = LAM2 + m * 192 + dir * 96;
            lam[0 * 32 + t] = v0;
            lam[1 * 32 + t] = v1;
            lam[2 * 32 + t] = v2;
        }
    }
}

// ---------------------------------------------------------------------------
// Kernel 4: MLP head. One block (64 threads) per image.
// ---------------------------------------------------------------------------
__global__ void mlp_kernel(const float* __restrict__ LAM1, const float* __restrict__ LAM2,
                           const float* __restrict__ w1, const float* __restrict__ b1,
                           const float* __restrict__ w2, const float* __restrict__ b2,
                           const float* __restrict__ wf, const float* __restrict__ bf,
                           float* __restrict__ out) {
    __shared__ float xc[64];
    int m = blockIdx.x;
    int n = threadIdx.x;
    if (n < 32) {
        float acc = b1[n];
        const float* l = LAM1 + m * 128;
        for (int c = 0; c < 128; ++c) acc += w1[n * 128 + c] * l[c];
        xc[n] = fmaxf(acc, 0.f);
    } else {
        int n2 = n - 32;
        float acc = b2[n2];
        const float* l = LAM2 + m * 192;
        for (int c = 0; c < 192; ++c) acc += w2[n2 * 192 + c] * l[c];
        xc[n] = fmaxf(acc, 0.f);
    }
    __syncthreads();
    if (n < 10) {
        float acc = bf[n];
        for (int c = 0; c < 64; ++c) acc += wf[n * 64 + c] * xc[c];
        out[m * 10 + n] = acc;
    }
}

extern "C" void kernel_launch(void* const* d_in, const int* in_sizes, int n_in,
                              void* d_out, int out_size, void* d_ws, size_t ws_size,
                              hipStream_t stream) {
    const float* x  = (const float*)d_in[0];
    const float* w1 = (const float*)d_in[1];
    const float* b1 = (const float*)d_in[2];
    const float* w2 = (const float*)d_in[3];
    const float* b2 = (const float*)d_in[4];
    const float* wf = (const float*)d_in[5];
    const float* bf = (const float*)d_in[6];
    float* out = (float*)d_out;

    char* ws = (char*)d_ws;
    size_t off = 0;
    unsigned short* SORT = (unsigned short*)(ws + off); off += (size_t)NPIX * NPIX * 2;
    unsigned short* D2S  = (unsigned short*)(ws + off); off += (size_t)NPIX * NPIX * 2;
    float* F    = (float*)(ws + off); off += (size_t)2 * NIMG * NPIX * 4;
    float* LAM1 = (float*)(ws + off); off += (size_t)NIMG * 128 * 4;
    float* LAM2 = (float*)(ws + off); off += (size_t)NIMG * 192 * 4;

    consts_kernel<<<NPIX, 256, 0, stream>>>(SORT, D2S);
    dtm_kernel<<<NIMG * NIG, 256, 0, stream>>>(x, SORT, D2S, F);
    uf_land_kernel<<<256, 256, 0, stream>>>(F, LAM1, LAM2);
    mlp_kernel<<<NIMG, 64, 0, stream>>>(LAM1, LAM2, w1, b1, w2, b2, wf, bf, out);
}

// Round 17
// 146.376 us; speedup vs baseline: 1.9570x; 1.0452x over previous
//
#include <hip/hip_runtime.h>

#define HW 28
#define NPIX 784   // 28*28
#define NIMG 64
#define MAXD2 1459 // d2 <= 2*27^2 = 1458
#define MAXREC 5504  // 783 * 7 worst case

// packed dx/dy (+1, 2 bits each) for {-1,0},{1,0},{0,-1},{0,1},
// {-1,-1},{-1,1},{1,-1},{1,1}; first 4 = 4-connectivity
#define DXPK 41048u
#define DYPK 34949u

// ---------------------------------------------------------------------------
// Kernel 1: distance-sort constants (counting sort, packed j|d2<<16) +
// per-image sums + x transpose, one dispatch (blocks [0,784)=consts,
// [784,848)=sums/transpose).
// ---------------------------------------------------------------------------
__global__ void consts_sums_kernel(unsigned int* __restrict__ TPK,
                                   const float* __restrict__ x,
                                   float* __restrict__ sums,
                                   float* __restrict__ xT) {
    int tid = threadIdx.x;
    if (blockIdx.x >= NPIX) {
        // ---- row sum + transpose for image m ----
        int m = blockIdx.x - NPIX;
        const float* xr = x + m * NPIX;
        float acc = 0.f;
        for (int j = tid; j < NPIX; j += 256) {
            float v = xr[j];
            xT[j * NIMG + m] = v;
            acc += v;
        }
        for (int off = 32; off > 0; off >>= 1) acc += __shfl_down(acc, off, 64);
        __shared__ float red[4];
        int lane = tid & 63, w = tid >> 6;
        if (lane == 0) red[w] = acc;
        __syncthreads();
        if (tid == 0) sums[m] = red[0] + red[1] + red[2] + red[3];
        return;
    }
    __shared__ int cnt[MAXD2];
    __shared__ int d2v[NPIX];
    __shared__ int wtot[4];
    int i = blockIdx.x;
    for (int b = tid; b < MAXD2; b += 256) cnt[b] = 0;
    __syncthreads();
    int ii = i / HW, ij = i % HW;
    for (int j = tid; j < NPIX; j += 256) {
        int di = ii - j / HW, dj = ij - j % HW;
        int d = di * di + dj * dj;
        d2v[j] = d;
        atomicAdd(&cnt[d], 1);
    }
    __syncthreads();
    int b0 = tid * 6;
    int lc[6];
    int s0 = 0;
    #pragma unroll
    for (int t = 0; t < 6; ++t) {
        int b = b0 + t;
        lc[t] = (b < MAXD2) ? cnt[b] : 0;
        s0 += lc[t];
    }
    int lane = tid & 63, wv = tid >> 6;
    int v = s0;
    for (int off = 1; off < 64; off <<= 1) {
        int t2 = __shfl_up(v, off, 64);
        if (lane >= off) v += t2;
    }
    if (lane == 63) wtot[wv] = v;
    __syncthreads();
    int wadd = 0;
    for (int w2 = 0; w2 < wv; ++w2) wadd += wtot[w2];
    int run = wadd + v - s0;
    __syncthreads();
    #pragma unroll
    for (int t = 0; t < 6; ++t) {
        int b = b0 + t;
        if (b < MAXD2) { cnt[b] = run; run += lc[t]; }
    }
    __syncthreads();
    for (int j = tid; j < NPIX; j += 256) {
        int d = d2v[j];
        int slot = atomicAdd(&cnt[d], 1);
        TPK[i * NPIX + slot] = (unsigned)j | ((unsigned)d << 16);
    }
}

// ---------------------------------------------------------------------------
// Kernel 2: DTM, transposed parallelism — one WAVE per pixel i, one LANE per
// image m. Table entry per step is wave-uniform (scalar load); the weight
// fetch xT[j*64+lane] is one coalesced 256B load; cum is a per-lane serial
// prefix (exact reference cumsum order; no shuffles). Early exit when all
// images reached bound2 (later eff terms exactly 0).
// ---------------------------------------------------------------------------
__global__ void __launch_bounds__(256) dtm_kernel(const unsigned int* __restrict__ TPK,
                                                  const float* __restrict__ xT,
                                                  const float* __restrict__ sums,
                                                  float* __restrict__ F) {
    int wv = threadIdx.x >> 6, lane = threadIdx.x & 63;
    int i = blockIdx.x * 4 + wv;           // grid 196 -> i in [0,784)
    float s = sums[lane];
    float bound1 = 0.05f * s, bound2 = 0.2f * s;
    const unsigned int* tp = TPK + (size_t)i * NPIX;
    float cum = 0.f, acc1 = 0.f, acc2 = 0.f;
    for (int t0 = 0; t0 < NPIX; t0 += 8) {   // 784 % 8 == 0
        unsigned int e[8];
        #pragma unroll
        for (int u = 0; u < 8; ++u) e[u] = tp[t0 + u];     // wave-uniform
        float w[8];
        #pragma unroll
        for (int u = 0; u < 8; ++u) w[u] = xT[(e[u] & 0xffffu) * NIMG + lane];
        #pragma unroll
        for (int u = 0; u < 8; ++u) {
            float d2 = (float)(e[u] >> 16);
            float ce = cum;
            cum += w[u];
            acc1 += fminf(fmaxf(bound1 - ce, 0.f), w[u]) * d2;
            acc2 += fminf(fmaxf(bound2 - ce, 0.f), w[u]) * d2;
        }
        if (__ballot(cum < bound2) == 0ull) break;  // all lanes done
    }
    F[0 * NIMG * NPIX + lane * NPIX + i] = sqrtf(acc1 / bound1);
    F[1 * NIMG * NPIX + lane * NPIX + i] = sqrtf(acc2 / bound2);
}

// ---------------------------------------------------------------------------
// Kernel 3: fused RANK + UF (basin decomposition) + LANDSCAPE.
// One 256-thread block per task. (Unchanged from round 16 — 58 µs.)
// ---------------------------------------------------------------------------
template<int NN>   // NN = 4 (dir 0) or 8 (dir 1)
__device__ int uf_basin_run(const int* posA, const int* ordA,
                            int* bas, unsigned int* pb, int* comp,
                            int* recs, int* pairsI,
                            int2* mergeLDS, int* shInts, int* wtot4) {
    const int tid = threadIdx.x;
    const int lane = tid & 63, wv = tid >> 6;

    // ---- P2: steepest-descent forest ----
    for (int s = tid; s < NPIX; s += 256) {
        int si = s / HW, sj = s % HW;
        int bestPos = posA[s], best = s;
        #pragma unroll
        for (int o = 0; o < NN; ++o) {
            int dx = ((DXPK >> (2 * o)) & 3) - 1;
            int dy = ((DYPK >> (2 * o)) & 3) - 1;
            int ui = si + dx, uj = sj + dy;
            if ((unsigned)ui < (unsigned)HW && (unsigned)uj < (unsigned)HW) {
                int u = ui * HW + uj;
                int pu = posA[u];
                if (pu < bestPos) { bestPos = pu; best = u; }
            }
        }
        bas[s] = best;
    }
    __syncthreads();

    // ---- P3: pointer jumping with convergence early-exit ----
    for (int it = 0; it < 10; ++it) {
        int changed = 0;
        for (int s = tid; s < NPIX; s += 256) {
            int b = bas[s];
            int bb = bas[b];
            if (bb != b) { bas[s] = bb; changed = 1; }
        }
        if (__syncthreads_count(changed) == 0) break;
    }

    // ---- pack (pos<<10 | bas) for single-gather P4 ----
    for (int s = tid; s < NPIX; s += 256)
        pb[s] = ((unsigned)posA[s] << 10) | (unsigned)bas[s];
    __syncthreads();

    // ---- P4: candidate records in rank order, block-scan compaction ----
    int nrec = 0;
    for (int c = 0; c < 4; ++c) {
        int r = c * 256 + tid;
        int cnt = 0;
        int myr[NN - 1];
        int got[NN - 1];
        #pragma unroll
        for (int t = 0; t < NN - 1; ++t) { got[t] = -1; myr[t] = 0; }
        if (r > 0 && r < NPIX) {
            int v = ordA[r];
            int vi = v / HW, vj = v % HW;
            int pivot = (int)(pb[v] & 1023u);
            #pragma unroll
            for (int o = 0; o < NN; ++o) {
                int dx = ((DXPK >> (2 * o)) & 3) - 1;
                int dy = ((DYPK >> (2 * o)) & 3) - 1;
                int ui = vi + dx, uj = vj + dy;
                if ((unsigned)ui < (unsigned)HW && (unsigned)uj < (unsigned)HW) {
                    int u = ui * HW + uj;
                    unsigned e = pb[u];
                    if ((int)(e >> 10) < r) {
                        int b = (int)(e & 1023u);
                        bool dup = (b == pivot);
                        #pragma unroll
                        for (int t = 0; t < NN - 1; ++t) dup = dup || (got[t] == b);
                        if (!dup) {
                            #pragma unroll
                            for (int t = 0; t < NN - 1; ++t)
                                if (t == cnt) { got[t] = b; myr[t] = (v << 20) | (pivot << 10) | b; }
                            cnt++;
                        }
                    }
                }
            }
        }
        // block-wide exclusive prefix of cnt
        int p = cnt;
        for (int off = 1; off < 64; off <<= 1) {
            int t2 = __shfl_up(p, off, 64);
            if (lane >= off) p += t2;
        }
        if (lane == 63) wtot4[wv] = p;
        __syncthreads();
        int wadd = 0;
        for (int w2 = 0; w2 < wv; ++w2) wadd += wtot4[w2];
        int tot = wtot4[0] + wtot4[1] + wtot4[2] + wtot4[3];
        int excl = wadd + p - cnt;
        #pragma unroll
        for (int t = 0; t < NN - 1; ++t)
            if (t < cnt) recs[nrec + excl + t] = myr[t];
        nrec += tot;
        __syncthreads();
    }

    // ---- P5: ballot-driven serial UF (wave 0), block-wide flatten ----
    int k = 0;
    for (int base = 0; base < nrec; base += 64) {
        int nrem = 0;
        if (wv == 0) {
            int idx = base + lane;
            int rec = (idx < nrec) ? recs[idx] : 0;
            int pa = (rec >> 10) & 1023, pbn = rec & 1023;
            int ka = 0, kb = 0;
            if (idx < nrec) { ka = comp[pa]; kb = comp[pbn]; }
            for (;;) {
                unsigned long long d = __ballot(ka != kb);
                if (d == 0ull) break;
                int i = (int)__ffsll((long long)d) - 1;   // lowest lane = lowest rank
                int sA = __builtin_amdgcn_readlane(ka, i);
                int sB = __builtin_amdgcn_readlane(kb, i);
                int w = min(sA, sB), l = max(sA, sB);     // uniform scalars
                int sv = __builtin_amdgcn_readlane(rec, i) >> 20;
                if (lane == 0) {
                    pairsI[k] = (l & 1023) | (sv << 10);
                    mergeLDS[nrem] = make_int2(l, w);
                }
                k++;
                ka = (ka == l) ? w : ka;
                kb = (kb == l) ? w : kb;
                nrem++;
                if (nrem == 63) {              // overflow guard (rare): wave-0 flatten
                    for (int s = lane; s < NPIX; s += 64) {
                        int cv = comp[s], c0 = cv;
                        for (int e = 0; e < nrem; ++e) {
                            int2 me = mergeLDS[e];
                            cv = (cv == me.x) ? me.y : cv;
                        }
                        if (cv != c0) comp[s] = cv;
                    }
                    if (idx < nrec) { ka = comp[pa]; kb = comp[pbn]; }
                    nrem = 0;
                }
            }
            if (lane == 0) shInts[0] = nrem;
        }
        __syncthreads();
        int nr = shInts[0];
        if (nr > 0) {                          // flatten with all 256 threads
            for (int s = tid; s < NPIX; s += 256) {
                int cv = comp[s], c0 = cv;
                for (int e = 0; e < nr; ++e) {
                    int2 me = mergeLDS[e];
                    cv = (cv == me.x) ? me.y : cv;
                }
                if (cv != c0) comp[s] = cv;
            }
        }
        __syncthreads();
    }
    if (tid == 0) shInts[1] = k;
    __syncthreads();
    return shInts[1];
}

__global__ void __launch_bounds__(256) uf_land_kernel(const float* __restrict__ F,
                                                      float* __restrict__ LAM1,
                                                      float* __restrict__ LAM2) {
    __shared__ int posA[NPIX], ordA[NPIX], bas[NPIX], comp[NPIX], pairsI[NPIX];
    __shared__ unsigned int ukey[NPIX];   // rank keys, then packed (pos,bas)
    __shared__ float fv[NPIX];
    __shared__ float2 pairs[NPIX];
    __shared__ int recs[MAXREC];
    __shared__ int2 mergeLDS[64];
    __shared__ int shInts[2];
    __shared__ int wtot4[4];
    int tid = threadIdx.x;
    int task = blockIdx.x;
    int feat = task >> 7;
    int dir = (task >> 6) & 1;
    int m = task & 63;
    const float* fr = F + feat * NIMG * NPIX + m * NPIX;

    // load values + dir-adjusted sortable keys (values >= 0: bits monotone)
    for (int j = tid; j < NPIX; j += 256) {
        float f = fr[j];
        fv[j] = f;
        unsigned int b = __float_as_uint(f);
        ukey[j] = dir ? ~b : b;
    }
    __syncthreads();

    // ---- fused rank (register-blocked, b128 LDS reads, u64 packed keys) ----
    {
        unsigned long long pki[4];
        int rank[4] = {0, 0, 0, 0};
        bool val[4];
        #pragma unroll
        for (int r = 0; r < 4; ++r) {
            int i = tid + 256 * r;
            val[r] = (i < NPIX);
            pki[r] = val[r] ? (((unsigned long long)ukey[i] << 10) | (unsigned)i) : 0ull;
        }
        const uint4* k4 = (const uint4*)ukey;
        for (int c = 0; c < NPIX / 4; ++c) {
            uint4 kv = k4[c];
            unsigned q = 4u * c;
            unsigned long long p0 = ((unsigned long long)kv.x << 10) | q;
            unsigned long long p1 = ((unsigned long long)kv.y << 10) | (q + 1);
            unsigned long long p2 = ((unsigned long long)kv.z << 10) | (q + 2);
            unsigned long long p3 = ((unsigned long long)kv.w << 10) | (q + 3);
            #pragma unroll
            for (int r = 0; r < 4; ++r) {
                rank[r] += (int)(p0 < pki[r]) + (int)(p1 < pki[r])
                         + (int)(p2 < pki[r]) + (int)(p3 < pki[r]);
            }
        }
        #pragma unroll
        for (int r = 0; r < 4; ++r) {
            if (val[r]) {
                int i = tid + 256 * r;
                posA[i] = rank[r];
                ordA[rank[r]] = i;
            }
        }
    }
    __syncthreads();
    for (int s = tid; s < NPIX; s += 256) comp[s] = (posA[s] << 10) | s;
    // (comp init needs no barrier before P2: P2 reads only posA)

    int k;
    if (dir == 0) k = uf_basin_run<4>(posA, ordA, bas, ukey, comp, recs, pairsI,
                                      mergeLDS, shInts, wtot4);
    else          k = uf_basin_run<8>(posA, ordA, bas, ukey, comp, recs, pairsI,
                                      mergeLDS, shInts, wtot4);

    // convert packed pairs to (b, d) float values (dir 1 stores swapped)
    for (int s = tid; s < k; s += 256) {
        int p = pairsI[s];
        float fb = fv[p & 1023], fd = fv[p >> 10];
        pairs[s] = dir ? make_float2(fd, fb) : make_float2(fb, fd);
    }
    __syncthreads();

    // ---- fused landscape: top-3 tents over the k real pairs ----
    if (tid < 32) {
        int t = tid;
        float start = (feat == 0) ? 0.f : 1.f;
        float end   = (feat == 0) ? 7.f : 8.f;
        float tv = start + (end - start) * ((float)t / 31.f);
        float v0 = 0.f, v1 = 0.f, v2 = 0.f;
        for (int p = 0; p < k; ++p) {
            float2 bd = pairs[p];
            float tent = fmaxf(fminf(tv - bd.x, bd.y - tv), 0.f);
            if (tent > v0)      { v2 = v1; v1 = v0; v0 = tent; }
            else if (tent > v1) { v2 = v1; v1 = tent; }
            else if (tent > v2) { v2 = tent; }
        }
        if (feat == 0) {
            float* lam = LAM1 + m * 128 + dir * 64;
            lam[0 * 32 + t] = v0;
            lam[1 * 32 + t] = v1;
        } else {
            float* lam = LAM2 + m * 192 + dir * 96;
            lam[0 * 32 + t] = v0;
            lam[1 * 32 + t] = v1;
            lam[2 * 32 + t] = v2;
        }
    }
}

// ---------------------------------------------------------------------------
// Kernel 4: MLP head. One block (64 threads) per image.
// ---------------------------------------------------------------------------
__global__ void mlp_kernel(const float* __restrict__ LAM1, const float* __restrict__ LAM2,
                           const float* __restrict__ w1, const float* __restrict__ b1,
                           const float* __restrict__ w2, const float* __restrict__ b2,
                           const float* __restrict__ wf, const float* __restrict__ bf,
                           float* __restrict__ out) {
    __shared__ float xc[64];
    int m = blockIdx.x;
    int n = threadIdx.x;
    if (n < 32) {
        float acc = b1[n];
        const float* l = LAM1 + m * 128;
        for (int c = 0; c < 128; ++c) acc += w1[n * 128 + c] * l[c];
        xc[n] = fmaxf(acc, 0.f);
    } else {
        int n2 = n - 32;
        float acc = b2[n2];
        const float* l = LAM2 + m * 192;
        for (int c = 0; c < 192; ++c) acc += w2[n2 * 192 + c] * l[c];
        xc[n] = fmaxf(acc, 0.f);
    }
    __syncthreads();
    if (n < 10) {
        float acc = bf[n];
        for (int c = 0; c < 64; ++c) acc += wf[n * 64 + c] * xc[c];
        out[m * 10 + n] = acc;
    }
}

extern "C" void kernel_launch(void* const* d_in, const int* in_sizes, int n_in,
                              void* d_out, int out_size, void* d_ws, size_t ws_size,
                              hipStream_t stream) {
    const float* x  = (const float*)d_in[0];
    const float* w1 = (const float*)d_in[1];
    const float* b1 = (const float*)d_in[2];
    const float* w2 = (const float*)d_in[3];
    const float* b2 = (const float*)d_in[4];
    const float* wf = (const float*)d_in[5];
    const float* bf = (const float*)d_in[6];
    float* out = (float*)d_out;

    char* ws = (char*)d_ws;
    size_t off = 0;
    unsigned int* TPK = (unsigned int*)(ws + off); off += (size_t)NPIX * NPIX * 4;
    float* XT   = (float*)(ws + off); off += (size_t)NPIX * NIMG * 4;
    float* SUMS = (float*)(ws + off); off += 256;
    float* F    = (float*)(ws + off); off += (size_t)2 * NIMG * NPIX * 4;
    float* LAM1 = (float*)(ws + off); off += (size_t)NIMG * 128 * 4;
    float* LAM2 = (float*)(ws + off); off += (size_t)NIMG * 192 * 4;

    consts_sums_kernel<<<NPIX + NIMG, 256, 0, stream>>>(TPK, x, SUMS, XT);
    dtm_kernel<<<NPIX / 4, 256, 0, stream>>>(TPK, XT, SUMS, F);
    uf_land_kernel<<<256, 256, 0, stream>>>(F, LAM1, LAM2);
    mlp_kernel<<<NIMG, 64, 0, stream>>>(LAM1, LAM2, w1, b1, w2, b2, wf, bf, out);
}

// Round 18
// 138.839 us; speedup vs baseline: 2.0632x; 1.0543x over previous
//
#include <hip/hip_runtime.h>

#define HW 28
#define NPIX 784   // 28*28
#define NIMG 64
#define MAXD2 1459 // d2 <= 2*27^2 = 1458
#define MAXREC 5504  // 783 * 7 worst case

// packed dx/dy (+1, 2 bits each) for {-1,0},{1,0},{0,-1},{0,1},
// {-1,-1},{-1,1},{1,-1},{1,1}; first 4 = 4-connectivity
#define DXPK 41048u
#define DYPK 34949u

// ---------------------------------------------------------------------------
// Kernel 1: distance-sort constants (counting sort, packed j|d2<<16) +
// per-image sums + x transpose, one dispatch.
// ---------------------------------------------------------------------------
__global__ void consts_sums_kernel(unsigned int* __restrict__ TPK,
                                   const float* __restrict__ x,
                                   float* __restrict__ sums,
                                   float* __restrict__ xT) {
    int tid = threadIdx.x;
    if (blockIdx.x >= NPIX) {
        int m = blockIdx.x - NPIX;
        const float* xr = x + m * NPIX;
        float acc = 0.f;
        for (int j = tid; j < NPIX; j += 256) {
            float v = xr[j];
            xT[j * NIMG + m] = v;
            acc += v;
        }
        for (int off = 32; off > 0; off >>= 1) acc += __shfl_down(acc, off, 64);
        __shared__ float red[4];
        int lane = tid & 63, w = tid >> 6;
        if (lane == 0) red[w] = acc;
        __syncthreads();
        if (tid == 0) sums[m] = red[0] + red[1] + red[2] + red[3];
        return;
    }
    __shared__ int cnt[MAXD2];
    __shared__ int d2v[NPIX];
    __shared__ int wtot[4];
    int i = blockIdx.x;
    for (int b = tid; b < MAXD2; b += 256) cnt[b] = 0;
    __syncthreads();
    int ii = i / HW, ij = i % HW;
    for (int j = tid; j < NPIX; j += 256) {
        int di = ii - j / HW, dj = ij - j % HW;
        int d = di * di + dj * dj;
        d2v[j] = d;
        atomicAdd(&cnt[d], 1);
    }
    __syncthreads();
    int b0 = tid * 6;
    int lc[6];
    int s0 = 0;
    #pragma unroll
    for (int t = 0; t < 6; ++t) {
        int b = b0 + t;
        lc[t] = (b < MAXD2) ? cnt[b] : 0;
        s0 += lc[t];
    }
    int lane = tid & 63, wv = tid >> 6;
    int v = s0;
    for (int off = 1; off < 64; off <<= 1) {
        int t2 = __shfl_up(v, off, 64);
        if (lane >= off) v += t2;
    }
    if (lane == 63) wtot[wv] = v;
    __syncthreads();
    int wadd = 0;
    for (int w2 = 0; w2 < wv; ++w2) wadd += wtot[w2];
    int run = wadd + v - s0;
    __syncthreads();
    #pragma unroll
    for (int t = 0; t < 6; ++t) {
        int b = b0 + t;
        if (b < MAXD2) { cnt[b] = run; run += lc[t]; }
    }
    __syncthreads();
    for (int j = tid; j < NPIX; j += 256) {
        int d = d2v[j];
        int slot = atomicAdd(&cnt[d], 1);
        TPK[i * NPIX + slot] = (unsigned)j | ((unsigned)d << 16);
    }
}

// ---------------------------------------------------------------------------
// Kernel 2: DTM, transposed — ONE WAVE (block) per pixel, one lane per image.
// 784 blocks -> ~3 blocks/CU: cross-block latency overlap.
// ---------------------------------------------------------------------------
__global__ void __launch_bounds__(64) dtm_kernel(const unsigned int* __restrict__ TPK,
                                                 const float* __restrict__ xT,
                                                 const float* __restrict__ sums,
                                                 float* __restrict__ F) {
    int lane = threadIdx.x;
    int i = blockIdx.x;
    float s = sums[lane];
    float bound1 = 0.05f * s, bound2 = 0.2f * s;
    const unsigned int* tp = TPK + (size_t)i * NPIX;
    float cum = 0.f, acc1 = 0.f, acc2 = 0.f;
    for (int t0 = 0; t0 < NPIX; t0 += 8) {   // 784 % 8 == 0
        unsigned int e[8];
        #pragma unroll
        for (int u = 0; u < 8; ++u) e[u] = tp[t0 + u];     // wave-uniform
        float w[8];
        #pragma unroll
        for (int u = 0; u < 8; ++u) w[u] = xT[(e[u] & 0xffffu) * NIMG + lane];
        #pragma unroll
        for (int u = 0; u < 8; ++u) {
            float d2 = (float)(e[u] >> 16);
            float ce = cum;
            cum += w[u];
            acc1 += fminf(fmaxf(bound1 - ce, 0.f), w[u]) * d2;
            acc2 += fminf(fmaxf(bound2 - ce, 0.f), w[u]) * d2;
        }
        if (__ballot(cum < bound2) == 0ull) break;  // all lanes done
    }
    F[0 * NIMG * NPIX + lane * NPIX + i] = sqrtf(acc1 / bound1);
    F[1 * NIMG * NPIX + lane * NPIX + i] = sqrtf(acc2 / bound2);
}

// ---------------------------------------------------------------------------
// Kernel 3: fused RANK + UF (basin decomposition) + LANDSCAPE.
// NOW 512 THREADS (8 waves, 2 waves/SIMD): same total VALU work, but a
// second wave per SIMD hides LDS-latency and barrier stalls that made the
// 256-thread version 73% idle (r17: VALUBusy 27%).
// ---------------------------------------------------------------------------
template<int NN>   // NN = 4 (dir 0) or 8 (dir 1)
__device__ int uf_basin_run(const int* posA, const int* ordA,
                            int* bas, unsigned int* pb, int* comp,
                            int* recs, int* pairsI,
                            int2* mergeLDS, int* shInts, int* wtot8) {
    const int tid = threadIdx.x;
    const int lane = tid & 63, wv = tid >> 6;   // wv in [0,8)

    // ---- P2: steepest-descent forest ----
    for (int s = tid; s < NPIX; s += 512) {
        int si = s / HW, sj = s % HW;
        int bestPos = posA[s], best = s;
        #pragma unroll
        for (int o = 0; o < NN; ++o) {
            int dx = ((DXPK >> (2 * o)) & 3) - 1;
            int dy = ((DYPK >> (2 * o)) & 3) - 1;
            int ui = si + dx, uj = sj + dy;
            if ((unsigned)ui < (unsigned)HW && (unsigned)uj < (unsigned)HW) {
                int u = ui * HW + uj;
                int pu = posA[u];
                if (pu < bestPos) { bestPos = pu; best = u; }
            }
        }
        bas[s] = best;
    }
    __syncthreads();

    // ---- P3: pointer jumping with convergence early-exit ----
    for (int it = 0; it < 10; ++it) {
        int changed = 0;
        for (int s = tid; s < NPIX; s += 512) {
            int b = bas[s];
            int bb = bas[b];
            if (bb != b) { bas[s] = bb; changed = 1; }
        }
        if (__syncthreads_count(changed) == 0) break;
    }

    // ---- pack (pos<<10 | bas) for single-gather P4 ----
    for (int s = tid; s < NPIX; s += 512)
        pb[s] = ((unsigned)posA[s] << 10) | (unsigned)bas[s];
    __syncthreads();

    // ---- P4: candidate records in rank order, block-scan compaction ----
    int nrec = 0;
    for (int c = 0; c < 2; ++c) {
        int r = c * 512 + tid;
        int cnt = 0;
        int myr[NN - 1];
        int got[NN - 1];
        #pragma unroll
        for (int t = 0; t < NN - 1; ++t) { got[t] = -1; myr[t] = 0; }
        if (r > 0 && r < NPIX) {
            int v = ordA[r];
            int vi = v / HW, vj = v % HW;
            int pivot = (int)(pb[v] & 1023u);
            #pragma unroll
            for (int o = 0; o < NN; ++o) {
                int dx = ((DXPK >> (2 * o)) & 3) - 1;
                int dy = ((DYPK >> (2 * o)) & 3) - 1;
                int ui = vi + dx, uj = vj + dy;
                if ((unsigned)ui < (unsigned)HW && (unsigned)uj < (unsigned)HW) {
                    int u = ui * HW + uj;
                    unsigned e = pb[u];
                    if ((int)(e >> 10) < r) {
                        int b = (int)(e & 1023u);
                        bool dup = (b == pivot);
                        #pragma unroll
                        for (int t = 0; t < NN - 1; ++t) dup = dup || (got[t] == b);
                        if (!dup) {
                            #pragma unroll
                            for (int t = 0; t < NN - 1; ++t)
                                if (t == cnt) { got[t] = b; myr[t] = (v << 20) | (pivot << 10) | b; }
                            cnt++;
                        }
                    }
                }
            }
        }
        // block-wide exclusive prefix of cnt (8 wave partials)
        int p = cnt;
        for (int off = 1; off < 64; off <<= 1) {
            int t2 = __shfl_up(p, off, 64);
            if (lane >= off) p += t2;
        }
        if (lane == 63) wtot8[wv] = p;
        __syncthreads();
        int wadd = 0;
        for (int w2 = 0; w2 < wv; ++w2) wadd += wtot8[w2];
        int tot = 0;
        #pragma unroll
        for (int w2 = 0; w2 < 8; ++w2) tot += wtot8[w2];
        int excl = wadd + p - cnt;
        #pragma unroll
        for (int t = 0; t < NN - 1; ++t)
            if (t < cnt) recs[nrec + excl + t] = myr[t];
        nrec += tot;
        __syncthreads();
    }

    // ---- P5: ballot-driven serial UF (wave 0), block-wide flatten ----
    int k = 0;
    for (int base = 0; base < nrec; base += 64) {
        int nrem = 0;
        if (wv == 0) {
            int idx = base + lane;
            int rec = (idx < nrec) ? recs[idx] : 0;
            int pa = (rec >> 10) & 1023, pbn = rec & 1023;
            int ka = 0, kb = 0;
            if (idx < nrec) { ka = comp[pa]; kb = comp[pbn]; }
            for (;;) {
                unsigned long long d = __ballot(ka != kb);
                if (d == 0ull) break;
                int i = (int)__ffsll((long long)d) - 1;   // lowest lane = lowest rank
                int sA = __builtin_amdgcn_readlane(ka, i);
                int sB = __builtin_amdgcn_readlane(kb, i);
                int w = min(sA, sB), l = max(sA, sB);     // uniform scalars
                int sv = __builtin_amdgcn_readlane(rec, i) >> 20;
                if (lane == 0) {
                    pairsI[k] = (l & 1023) | (sv << 10);
                    mergeLDS[nrem] = make_int2(l, w);
                }
                k++;
                ka = (ka == l) ? w : ka;
                kb = (kb == l) ? w : kb;
                nrem++;
                if (nrem == 63) {              // overflow guard (rare): wave-0 flatten
                    for (int s = lane; s < NPIX; s += 64) {
                        int cv = comp[s], c0 = cv;
                        for (int e = 0; e < nrem; ++e) {
                            int2 me = mergeLDS[e];
                            cv = (cv == me.x) ? me.y : cv;
                        }
                        if (cv != c0) comp[s] = cv;
                    }
                    if (idx < nrec) { ka = comp[pa]; kb = comp[pbn]; }
                    nrem = 0;
                }
            }
            if (lane == 0) shInts[0] = nrem;
        }
        __syncthreads();
        int nr = shInts[0];
        if (nr > 0) {                          // flatten with all 512 threads
            for (int s = tid; s < NPIX; s += 512) {
                int cv = comp[s], c0 = cv;
                for (int e = 0; e < nr; ++e) {
                    int2 me = mergeLDS[e];
                    cv = (cv == me.x) ? me.y : cv;
                }
                if (cv != c0) comp[s] = cv;
            }
        }
        __syncthreads();
    }
    if (tid == 0) shInts[1] = k;
    __syncthreads();
    return shInts[1];
}

__global__ void __launch_bounds__(512) uf_land_kernel(const float* __restrict__ F,
                                                      float* __restrict__ LAM1,
                                                      float* __restrict__ LAM2) {
    __shared__ int posA[NPIX], ordA[NPIX], bas[NPIX], comp[NPIX], pairsI[NPIX];
    __shared__ unsigned int ukey[NPIX];   // rank keys, then packed (pos,bas)
    __shared__ float fv[NPIX];
    __shared__ float2 pairs[NPIX];
    __shared__ int recs[MAXREC];
    __shared__ int2 mergeLDS[64];
    __shared__ int shInts[2];
    __shared__ int wtot8[8];
    int tid = threadIdx.x;
    int task = blockIdx.x;
    int feat = task >> 7;
    int dir = (task >> 6) & 1;
    int m = task & 63;
    const float* fr = F + feat * NIMG * NPIX + m * NPIX;

    // load values + dir-adjusted sortable keys (values >= 0: bits monotone)
    for (int j = tid; j < NPIX; j += 512) {
        float f = fr[j];
        fv[j] = f;
        unsigned int b = __float_as_uint(f);
        ukey[j] = dir ? ~b : b;
    }
    __syncthreads();

    // ---- fused rank (2 rows/thread, b128 LDS reads, u64 packed keys) ----
    {
        unsigned long long pki[2];
        int rank[2] = {0, 0};
        bool val[2];
        #pragma unroll
        for (int r = 0; r < 2; ++r) {
            int i = tid + 512 * r;
            val[r] = (i < NPIX);
            pki[r] = val[r] ? (((unsigned long long)ukey[i] << 10) | (unsigned)i) : 0ull;
        }
        const uint4* k4 = (const uint4*)ukey;
        for (int c = 0; c < NPIX / 4; ++c) {
            uint4 kv = k4[c];
            unsigned q = 4u * c;
            unsigned long long p0 = ((unsigned long long)kv.x << 10) | q;
            unsigned long long p1 = ((unsigned long long)kv.y << 10) | (q + 1);
            unsigned long long p2 = ((unsigned long long)kv.z << 10) | (q + 2);
            unsigned long long p3 = ((unsigned long long)kv.w << 10) | (q + 3);
            #pragma unroll
            for (int r = 0; r < 2; ++r) {
                rank[r] += (int)(p0 < pki[r]) + (int)(p1 < pki[r])
                         + (int)(p2 < pki[r]) + (int)(p3 < pki[r]);
            }
        }
        #pragma unroll
        for (int r = 0; r < 2; ++r) {
            if (val[r]) {
                int i = tid + 512 * r;
                posA[i] = rank[r];
                ordA[rank[r]] = i;
            }
        }
    }
    __syncthreads();
    for (int s = tid; s < NPIX; s += 512) comp[s] = (posA[s] << 10) | s;
    // (comp init needs no barrier before P2: P2 reads only posA)

    int k;
    if (dir == 0) k = uf_basin_run<4>(posA, ordA, bas, ukey, comp, recs, pairsI,
                                      mergeLDS, shInts, wtot8);
    else          k = uf_basin_run<8>(posA, ordA, bas, ukey, comp, recs, pairsI,
                                      mergeLDS, shInts, wtot8);

    // convert packed pairs to (b, d) float values (dir 1 stores swapped)
    for (int s = tid; s < k; s += 512) {
        int p = pairsI[s];
        float fb = fv[p & 1023], fd = fv[p >> 10];
        pairs[s] = dir ? make_float2(fd, fb) : make_float2(fb, fd);
    }
    __syncthreads();

    // ---- fused landscape: top-3 tents over the k real pairs ----
    if (tid < 32) {
        int t = tid;
        float start = (feat == 0) ? 0.f : 1.f;
        float end   = (feat == 0) ? 7.f : 8.f;
        float tv = start + (end - start) * ((float)t / 31.f);
        float v0 = 0.f, v1 = 0.f, v2 = 0.f;
        for (int p = 0; p < k; ++p) {
            float2 bd = pairs[p];
            float tent = fmaxf(fminf(tv - bd.x, bd.y - tv), 0.f);
            if (tent > v0)      { v2 = v1; v1 = v0; v0 = tent; }
            else if (tent > v1) { v2 = v1; v1 = tent; }
            else if (tent > v2) { v2 = tent; }
        }
        if (feat == 0) {
            float* lam = LAM1 + m * 128 + dir * 64;
            lam[0 * 32 + t] = v0;
            lam[1 * 32 + t] = v1;
        } else {
            float* lam = LAM2 + m * 192 + dir * 96;
            lam[0 * 32 + t] = v0;
            lam[1 * 32 + t] = v1;
            lam[2 * 32 + t] = v2;
        }
    }
}

// ---------------------------------------------------------------------------
// Kernel 4: MLP head. One block (64 threads) per image.
// ---------------------------------------------------------------------------
__global__ void mlp_kernel(const float* __restrict__ LAM1, const float* __restrict__ LAM2,
                           const float* __restrict__ w1, const float* __restrict__ b1,
                           const float* __restrict__ w2, const float* __restrict__ b2,
                           const float* __restrict__ wf, const float* __restrict__ bf,
                           float* __restrict__ out) {
    __shared__ float xc[64];
    int m = blockIdx.x;
    int n = threadIdx.x;
    if (n < 32) {
        float acc = b1[n];
        const float* l = LAM1 + m * 128;
        for (int c = 0; c < 128; ++c) acc += w1[n * 128 + c] * l[c];
        xc[n] = fmaxf(acc, 0.f);
    } else {
        int n2 = n - 32;
        float acc = b2[n2];
        const float* l = LAM2 + m * 192;
        for (int c = 0; c < 192; ++c) acc += w2[n2 * 192 + c] * l[c];
        xc[n] = fmaxf(acc, 0.f);
    }
    __syncthreads();
    if (n < 10) {
        float acc = bf[n];
        for (int c = 0; c < 64; ++c) acc += wf[n * 64 + c] * xc[c];
        out[m * 10 + n] = acc;
    }
}

extern "C" void kernel_launch(void* const* d_in, const int* in_sizes, int n_in,
                              void* d_out, int out_size, void* d_ws, size_t ws_size,
                              hipStream_t stream) {
    const float* x  = (const float*)d_in[0];
    const float* w1 = (const float*)d_in[1];
    const float* b1 = (const float*)d_in[2];
    const float* w2 = (const float*)d_in[3];
    const float* b2 = (const float*)d_in[4];
    const float* wf = (const float*)d_in[5];
    const float* bf = (const float*)d_in[6];
    float* out = (float*)d_out;

    char* ws = (char*)d_ws;
    size_t off = 0;
    unsigned int* TPK = (unsigned int*)(ws + off); off += (size_t)NPIX * NPIX * 4;
    float* XT   = (float*)(ws + off); off += (size_t)NPIX * NIMG * 4;
    float* SUMS = (float*)(ws + off); off += 256;
    float* F    = (float*)(ws + off); off += (size_t)2 * NIMG * NPIX * 4;
    float* LAM1 = (float*)(ws + off); off += (size_t)NIMG * 128 * 4;
    float* LAM2 = (float*)(ws + off); off += (size_t)NIMG * 192 * 4;

    consts_sums_kernel<<<NPIX + NIMG, 256, 0, stream>>>(TPK, x, SUMS, XT);
    dtm_kernel<<<NPIX, 64, 0, stream>>>(TPK, XT, SUMS, F);
    uf_land_kernel<<<256, 512, 0, stream>>>(F, LAM1, LAM2);
    mlp_kernel<<<NIMG, 64, 0, stream>>>(LAM1, LAM2, w1, b1, w2, b2, wf, bf, out);
}

// Round 19
// 135.680 us; speedup vs baseline: 2.1113x; 1.0233x over previous
//
#include <hip/hip_runtime.h>

#define HW 28
#define NPIX 784   // 28*28
#define NIMG 64
#define MAXD2 1459 // d2 <= 2*27^2 = 1458
#define MAXREC 5504  // 783 * 7 worst case

// packed dx/dy (+1, 2 bits each) for {-1,0},{1,0},{0,-1},{0,1},
// {-1,-1},{-1,1},{1,-1},{1,1}; first 4 = 4-connectivity
#define DXPK 41048u
#define DYPK 34949u

// ---------------------------------------------------------------------------
// Kernel 1: per-image sums + x transpose (64 blocks).
// ---------------------------------------------------------------------------
__global__ void sums_transpose_kernel(const float* __restrict__ x,
                                      float* __restrict__ sums,
                                      float* __restrict__ xT) {
    int tid = threadIdx.x;
    int m = blockIdx.x;
    const float* xr = x + m * NPIX;
    float acc = 0.f;
    for (int j = tid; j < NPIX; j += 256) {
        float v = xr[j];
        xT[j * NIMG + m] = v;
        acc += v;
    }
    for (int off = 32; off > 0; off >>= 1) acc += __shfl_down(acc, off, 64);
    __shared__ float red[4];
    int lane = tid & 63, w = tid >> 6;
    if (lane == 0) red[w] = acc;
    __syncthreads();
    if (tid == 0) sums[m] = red[0] + red[1] + red[2] + red[3];
}

// ---------------------------------------------------------------------------
// Kernel 2: DTM with FUSED per-pixel counting sort. One WAVE (block) per
// pixel i, one lane per image. The distance sort (previously a separate
// dispatch + 2.4MB global round-trip) runs barrier-free in-wave: 13-elem/lane
// LDS-atomic histogram, 23-bin/lane serial + wave-scan prefix, scatter into
// LDS tpk. Bin-tie order is irrelevant (d2 constant within bin => exact
// water-fill invariance). Then the scan: table entries are wave-uniform LDS
// broadcasts; weight fetch is one coalesced 256B load; per-lane serial cum
// (exact reference cumsum order). Early exit when all images hit bound2.
// ---------------------------------------------------------------------------
__global__ void __launch_bounds__(64) dtm_kernel(const float* __restrict__ xT,
                                                 const float* __restrict__ sums,
                                                 float* __restrict__ F) {
    __shared__ int cnt[MAXD2];
    __shared__ unsigned int tpk[NPIX];
    int lane = threadIdx.x;
    int i = blockIdx.x;
    int ii = i / HW, ij = i % HW;

    // zero bins
    for (int b = lane; b < MAXD2; b += 64) cnt[b] = 0;
    // histogram (13 elems/lane; same-wave LDS ops are program-ordered)
    int dloc[13], jloc[13];
    #pragma unroll
    for (int u = 0; u < 13; ++u) {
        int j = u * 64 + lane;
        int d = 0;
        if (j < NPIX) {
            int di = ii - j / HW, dj = ij - j % HW;
            d = di * di + dj * dj;
            atomicAdd(&cnt[d], 1);
        }
        dloc[u] = d; jloc[u] = j;
    }
    // exclusive prefix over bins: lane owns [lane*23, lane*23+23)
    int b0 = lane * 23;
    int lsum = 0;
    #pragma unroll
    for (int t = 0; t < 23; ++t) {
        int b = b0 + t;
        if (b < MAXD2) lsum += cnt[b];
    }
    int v = lsum;
    for (int off = 1; off < 64; off <<= 1) {
        int t2 = __shfl_up(v, off, 64);
        if (lane >= off) v += t2;
    }
    int run = v - lsum;
    #pragma unroll
    for (int t = 0; t < 23; ++t) {
        int b = b0 + t;
        if (b < MAXD2) { int c = cnt[b]; cnt[b] = run; run += c; }
    }
    // scatter (tie order within bin unordered — exact by bin-invariance)
    #pragma unroll
    for (int u = 0; u < 13; ++u) {
        if (jloc[u] < NPIX) {
            int slot = atomicAdd(&cnt[dloc[u]], 1);
            tpk[slot] = (unsigned)jloc[u] | ((unsigned)dloc[u] << 16);
        }
    }

    // ---- DTM scan ----
    float s = sums[lane];
    float bound1 = 0.05f * s, bound2 = 0.2f * s;
    float cum = 0.f, acc1 = 0.f, acc2 = 0.f;
    for (int t0 = 0; t0 < NPIX; t0 += 8) {   // 784 % 8 == 0
        unsigned int e[8];
        #pragma unroll
        for (int u = 0; u < 8; ++u) e[u] = tpk[t0 + u];    // wave-uniform
        float w[8];
        #pragma unroll
        for (int u = 0; u < 8; ++u) w[u] = xT[(e[u] & 0xffffu) * NIMG + lane];
        #pragma unroll
        for (int u = 0; u < 8; ++u) {
            float d2 = (float)(e[u] >> 16);
            float ce = cum;
            cum += w[u];
            acc1 += fminf(fmaxf(bound1 - ce, 0.f), w[u]) * d2;
            acc2 += fminf(fmaxf(bound2 - ce, 0.f), w[u]) * d2;
        }
        if (__ballot(cum < bound2) == 0ull) break;  // all lanes done
    }
    F[0 * NIMG * NPIX + lane * NPIX + i] = sqrtf(acc1 / bound1);
    F[1 * NIMG * NPIX + lane * NPIX + i] = sqrtf(acc2 / bound2);
}

// ---------------------------------------------------------------------------
// Kernel 3: fused RANK + UF (basin decomposition) + LANDSCAPE.
// NOW 1024 THREADS (16 waves, 4 waves/SIMD): r18 showed waves/SIMD is the
// stall-compression lever (27->36% VALUBusy going 1->2 waves/SIMD).
// ---------------------------------------------------------------------------
template<int NN>   // NN = 4 (dir 0) or 8 (dir 1)
__device__ int uf_basin_run(const int* posA, const int* ordA,
                            int* bas, unsigned int* pb, int* comp,
                            int* recs, int* pairsI,
                            int2* mergeLDS, int* shInts, int* wtot16) {
    const int tid = threadIdx.x;
    const int lane = tid & 63, wv = tid >> 6;   // wv in [0,16)

    // ---- P2: steepest-descent forest ----
    for (int s = tid; s < NPIX; s += 1024) {
        int si = s / HW, sj = s % HW;
        int bestPos = posA[s], best = s;
        #pragma unroll
        for (int o = 0; o < NN; ++o) {
            int dx = ((DXPK >> (2 * o)) & 3) - 1;
            int dy = ((DYPK >> (2 * o)) & 3) - 1;
            int ui = si + dx, uj = sj + dy;
            if ((unsigned)ui < (unsigned)HW && (unsigned)uj < (unsigned)HW) {
                int u = ui * HW + uj;
                int pu = posA[u];
                if (pu < bestPos) { bestPos = pu; best = u; }
            }
        }
        bas[s] = best;
    }
    __syncthreads();

    // ---- P3: pointer jumping with convergence early-exit ----
    for (int it = 0; it < 10; ++it) {
        int changed = 0;
        for (int s = tid; s < NPIX; s += 1024) {
            int b = bas[s];
            int bb = bas[b];
            if (bb != b) { bas[s] = bb; changed = 1; }
        }
        if (__syncthreads_count(changed) == 0) break;
    }

    // ---- pack (pos<<10 | bas) for single-gather P4 ----
    for (int s = tid; s < NPIX; s += 1024)
        pb[s] = ((unsigned)posA[s] << 10) | (unsigned)bas[s];
    __syncthreads();

    // ---- P4: candidate records in rank order (single pass, r = tid) ----
    int nrec = 0;
    {
        int r = tid;
        int cnt = 0;
        int myr[NN - 1];
        int got[NN - 1];
        #pragma unroll
        for (int t = 0; t < NN - 1; ++t) { got[t] = -1; myr[t] = 0; }
        if (r > 0 && r < NPIX) {
            int v = ordA[r];
            int vi = v / HW, vj = v % HW;
            int pivot = (int)(pb[v] & 1023u);
            #pragma unroll
            for (int o = 0; o < NN; ++o) {
                int dx = ((DXPK >> (2 * o)) & 3) - 1;
                int dy = ((DYPK >> (2 * o)) & 3) - 1;
                int ui = vi + dx, uj = vj + dy;
                if ((unsigned)ui < (unsigned)HW && (unsigned)uj < (unsigned)HW) {
                    int u = ui * HW + uj;
                    unsigned e = pb[u];
                    if ((int)(e >> 10) < r) {
                        int b = (int)(e & 1023u);
                        bool dup = (b == pivot);
                        #pragma unroll
                        for (int t = 0; t < NN - 1; ++t) dup = dup || (got[t] == b);
                        if (!dup) {
                            #pragma unroll
                            for (int t = 0; t < NN - 1; ++t)
                                if (t == cnt) { got[t] = b; myr[t] = (v << 20) | (pivot << 10) | b; }
                            cnt++;
                        }
                    }
                }
            }
        }
        // block-wide exclusive prefix of cnt (16 wave partials)
        int p = cnt;
        for (int off = 1; off < 64; off <<= 1) {
            int t2 = __shfl_up(p, off, 64);
            if (lane >= off) p += t2;
        }
        if (lane == 63) wtot16[wv] = p;
        __syncthreads();
        int wadd = 0;
        for (int w2 = 0; w2 < wv; ++w2) wadd += wtot16[w2];
        int tot = 0;
        #pragma unroll
        for (int w2 = 0; w2 < 16; ++w2) tot += wtot16[w2];
        int excl = wadd + p - cnt;
        #pragma unroll
        for (int t = 0; t < NN - 1; ++t)
            if (t < cnt) recs[excl + t] = myr[t];
        nrec = tot;
        __syncthreads();
    }

    // ---- P5: ballot-driven serial UF (wave 0), block-wide flatten ----
    int k = 0;
    for (int base = 0; base < nrec; base += 64) {
        int nrem = 0;
        if (wv == 0) {
            int idx = base + lane;
            int rec = (idx < nrec) ? recs[idx] : 0;
            int pa = (rec >> 10) & 1023, pbn = rec & 1023;
            int ka = 0, kb = 0;
            if (idx < nrec) { ka = comp[pa]; kb = comp[pbn]; }
            for (;;) {
                unsigned long long d = __ballot(ka != kb);
                if (d == 0ull) break;
                int i = (int)__ffsll((long long)d) - 1;   // lowest lane = lowest rank
                int sA = __builtin_amdgcn_readlane(ka, i);
                int sB = __builtin_amdgcn_readlane(kb, i);
                int w = min(sA, sB), l = max(sA, sB);     // uniform scalars
                int sv = __builtin_amdgcn_readlane(rec, i) >> 20;
                if (lane == 0) {
                    pairsI[k] = (l & 1023) | (sv << 10);
                    mergeLDS[nrem] = make_int2(l, w);
                }
                k++;
                ka = (ka == l) ? w : ka;
                kb = (kb == l) ? w : kb;
                nrem++;
                if (nrem == 63) {              // overflow guard (rare): wave-0 flatten
                    for (int s = lane; s < NPIX; s += 64) {
                        int cv = comp[s], c0 = cv;
                        for (int e = 0; e < nrem; ++e) {
                            int2 me = mergeLDS[e];
                            cv = (cv == me.x) ? me.y : cv;
                        }
                        if (cv != c0) comp[s] = cv;
                    }
                    if (idx < nrec) { ka = comp[pa]; kb = comp[pbn]; }
                    nrem = 0;
                }
            }
            if (lane == 0) shInts[0] = nrem;
        }
        __syncthreads();
        int nr = shInts[0];
        if (nr > 0) {                          // flatten with all 1024 threads
            for (int s = tid; s < NPIX; s += 1024) {
                int cv = comp[s], c0 = cv;
                for (int e = 0; e < nr; ++e) {
                    int2 me = mergeLDS[e];
                    cv = (cv == me.x) ? me.y : cv;
                }
                if (cv != c0) comp[s] = cv;
            }
        }
        __syncthreads();
    }
    if (tid == 0) shInts[1] = k;
    __syncthreads();
    return shInts[1];
}

__global__ void __launch_bounds__(1024) uf_land_kernel(const float* __restrict__ F,
                                                       float* __restrict__ LAM1,
                                                       float* __restrict__ LAM2) {
    __shared__ int posA[NPIX], ordA[NPIX], bas[NPIX], comp[NPIX], pairsI[NPIX];
    __shared__ unsigned int ukey[NPIX];   // rank keys, then packed (pos,bas)
    __shared__ float fv[NPIX];
    __shared__ float2 pairs[NPIX];
    __shared__ int recs[MAXREC];
    __shared__ int2 mergeLDS[64];
    __shared__ int shInts[2];
    __shared__ int wtot16[16];
    int tid = threadIdx.x;
    int task = blockIdx.x;
    int feat = task >> 7;
    int dir = (task >> 6) & 1;
    int m = task & 63;
    const float* fr = F + feat * NIMG * NPIX + m * NPIX;

    // load values + dir-adjusted sortable keys (values >= 0: bits monotone)
    for (int j = tid; j < NPIX; j += 1024) {
        float f = fr[j];
        fv[j] = f;
        unsigned int b = __float_as_uint(f);
        ukey[j] = dir ? ~b : b;
    }
    __syncthreads();

    // ---- fused rank (1 row/thread, b128 LDS reads, u64 packed keys) ----
    {
        bool val = (tid < NPIX);
        unsigned long long pki = val
            ? (((unsigned long long)ukey[tid] << 10) | (unsigned)tid) : 0ull;
        int rank = 0;
        const uint4* k4 = (const uint4*)ukey;
        for (int c = 0; c < NPIX / 4; ++c) {
            uint4 kv = k4[c];
            unsigned q = 4u * c;
            unsigned long long p0 = ((unsigned long long)kv.x << 10) | q;
            unsigned long long p1 = ((unsigned long long)kv.y << 10) | (q + 1);
            unsigned long long p2 = ((unsigned long long)kv.z << 10) | (q + 2);
            unsigned long long p3 = ((unsigned long long)kv.w << 10) | (q + 3);
            rank += (int)(p0 < pki) + (int)(p1 < pki)
                  + (int)(p2 < pki) + (int)(p3 < pki);
        }
        if (val) {
            posA[tid] = rank;
            ordA[rank] = tid;
        }
    }
    __syncthreads();
    for (int s = tid; s < NPIX; s += 1024) comp[s] = (posA[s] << 10) | s;
    // (comp init needs no barrier before P2: P2 reads only posA)

    int k;
    if (dir == 0) k = uf_basin_run<4>(posA, ordA, bas, ukey, comp, recs, pairsI,
                                      mergeLDS, shInts, wtot16);
    else          k = uf_basin_run<8>(posA, ordA, bas, ukey, comp, recs, pairsI,
                                      mergeLDS, shInts, wtot16);

    // convert packed pairs to (b, d) float values (dir 1 stores swapped)
    for (int s = tid; s < k; s += 1024) {
        int p = pairsI[s];
        float fb = fv[p & 1023], fd = fv[p >> 10];
        pairs[s] = dir ? make_float2(fd, fb) : make_float2(fb, fd);
    }
    __syncthreads();

    // ---- fused landscape: top-3 tents over the k real pairs ----
    if (tid < 32) {
        int t = tid;
        float start = (feat == 0) ? 0.f : 1.f;
        float end   = (feat == 0) ? 7.f : 8.f;
        float tv = start + (end - start) * ((float)t / 31.f);
        float v0 = 0.f, v1 = 0.f, v2 = 0.f;
        for (int p = 0; p < k; ++p) {
            float2 bd = pairs[p];
            float tent = fmaxf(fminf(tv - bd.x, bd.y - tv), 0.f);
            if (tent > v0)      { v2 = v1; v1 = v0; v0 = tent; }
            else if (tent > v1) { v2 = v1; v1 = tent; }
            else if (tent > v2) { v2 = tent; }
        }
        if (feat == 0) {
            float* lam = LAM1 + m * 128 + dir * 64;
            lam[0 * 32 + t] = v0;
            lam[1 * 32 + t] = v1;
        } else {
            float* lam = LAM2 + m * 192 + dir * 96;
            lam[0 * 32 + t] = v0;
            lam[1 * 32 + t] = v1;
            lam[2 * 32 + t] = v2;
        }
    }
}

// ---------------------------------------------------------------------------
// Kernel 4: MLP head. One block (64 threads) per image.
// ---------------------------------------------------------------------------
__global__ void mlp_kernel(const float* __restrict__ LAM1, const float* __restrict__ LAM2,
                           const float* __restrict__ w1, const float* __restrict__ b1,
                           const float* __restrict__ w2, const float* __restrict__ b2,
                           const float* __restrict__ wf, const float* __restrict__ bf,
                           float* __restrict__ out) {
    __shared__ float xc[64];
    int m = blockIdx.x;
    int n = threadIdx.x;
    if (n < 32) {
        float acc = b1[n];
        const float* l = LAM1 + m * 128;
        for (int c = 0; c < 128; ++c) acc += w1[n * 128 + c] * l[c];
        xc[n] = fmaxf(acc, 0.f);
    } else {
        int n2 = n - 32;
        float acc = b2[n2];
        const float* l = LAM2 + m * 192;
        for (int c = 0; c < 192; ++c) acc += w2[n2 * 192 + c] * l[c];
        xc[n] = fmaxf(acc, 0.f);
    }
    __syncthreads();
    if (n < 10) {
        float acc = bf[n];
        for (int c = 0; c < 64; ++c) acc += wf[n * 64 + c] * xc[c];
        out[m * 10 + n] = acc;
    }
}

extern "C" void kernel_launch(void* const* d_in, const int* in_sizes, int n_in,
                              void* d_out, int out_size, void* d_ws, size_t ws_size,
                              hipStream_t stream) {
    const float* x  = (const float*)d_in[0];
    const float* w1 = (const float*)d_in[1];
    const float* b1 = (const float*)d_in[2];
    const float* w2 = (const float*)d_in[3];
    const float* b2 = (const float*)d_in[4];
    const float* wf = (const float*)d_in[5];
    const float* bf = (const float*)d_in[6];
    float* out = (float*)d_out;

    char* ws = (char*)d_ws;
    size_t off = 0;
    float* XT   = (float*)(ws + off); off += (size_t)NPIX * NIMG * 4;
    float* SUMS = (float*)(ws + off); off += 256;
    float* F    = (float*)(ws + off); off += (size_t)2 * NIMG * NPIX * 4;
    float* LAM1 = (float*)(ws + off); off += (size_t)NIMG * 128 * 4;
    float* LAM2 = (float*)(ws + off); off += (size_t)NIMG * 192 * 4;

    sums_transpose_kernel<<<NIMG, 256, 0, stream>>>(x, SUMS, XT);
    dtm_kernel<<<NPIX, 64, 0, stream>>>(XT, SUMS, F);
    uf_land_kernel<<<256, 1024, 0, stream>>>(F, LAM1, LAM2);
    mlp_kernel<<<NIMG, 64, 0, stream>>>(LAM1, LAM2, w1, b1, w2, b2, wf, bf, out);
}

// Round 20
// 122.567 us; speedup vs baseline: 2.3371x; 1.1070x over previous
//
#include <hip/hip_runtime.h>

#define HW 28
#define NPIX 784   // 28*28
#define NIMG 64
#define MAXD2 1459 // d2 <= 2*27^2 = 1458
#define MAXREC 5504  // 783 * 7 worst case

// packed dx/dy (+1, 2 bits each) for {-1,0},{1,0},{0,-1},{0,1},
// {-1,-1},{-1,1},{1,-1},{1,1}; first 4 = 4-connectivity
#define DXPK 41048u
#define DYPK 34949u

// ---------------------------------------------------------------------------
// Kernel 1: distance-sort constants (counting sort, packed j|d2<<16) +
// per-image sums + x transpose, one dispatch (shared sort is cheaper than
// per-pixel in-dtm sorts — r19 lesson: that fusion cost +6 µs).
// ---------------------------------------------------------------------------
__global__ void consts_sums_kernel(unsigned int* __restrict__ TPK,
                                   const float* __restrict__ x,
                                   float* __restrict__ sums,
                                   float* __restrict__ xT) {
    int tid = threadIdx.x;
    if (blockIdx.x >= NPIX) {
        int m = blockIdx.x - NPIX;
        const float* xr = x + m * NPIX;
        float acc = 0.f;
        for (int j = tid; j < NPIX; j += 256) {
            float v = xr[j];
            xT[j * NIMG + m] = v;
            acc += v;
        }
        for (int off = 32; off > 0; off >>= 1) acc += __shfl_down(acc, off, 64);
        __shared__ float red[4];
        int lane = tid & 63, w = tid >> 6;
        if (lane == 0) red[w] = acc;
        __syncthreads();
        if (tid == 0) sums[m] = red[0] + red[1] + red[2] + red[3];
        return;
    }
    __shared__ int cnt[MAXD2];
    __shared__ int d2v[NPIX];
    __shared__ int wtot[4];
    int i = blockIdx.x;
    for (int b = tid; b < MAXD2; b += 256) cnt[b] = 0;
    __syncthreads();
    int ii = i / HW, ij = i % HW;
    for (int j = tid; j < NPIX; j += 256) {
        int di = ii - j / HW, dj = ij - j % HW;
        int d = di * di + dj * dj;
        d2v[j] = d;
        atomicAdd(&cnt[d], 1);
    }
    __syncthreads();
    int b0 = tid * 6;
    int lc[6];
    int s0 = 0;
    #pragma unroll
    for (int t = 0; t < 6; ++t) {
        int b = b0 + t;
        lc[t] = (b < MAXD2) ? cnt[b] : 0;
        s0 += lc[t];
    }
    int lane = tid & 63, wv = tid >> 6;
    int v = s0;
    for (int off = 1; off < 64; off <<= 1) {
        int t2 = __shfl_up(v, off, 64);
        if (lane >= off) v += t2;
    }
    if (lane == 63) wtot[wv] = v;
    __syncthreads();
    int wadd = 0;
    for (int w2 = 0; w2 < wv; ++w2) wadd += wtot[w2];
    int run = wadd + v - s0;
    __syncthreads();
    #pragma unroll
    for (int t = 0; t < 6; ++t) {
        int b = b0 + t;
        if (b < MAXD2) { cnt[b] = run; run += lc[t]; }
    }
    __syncthreads();
    for (int j = tid; j < NPIX; j += 256) {
        int d = d2v[j];
        int slot = atomicAdd(&cnt[d], 1);
        TPK[i * NPIX + slot] = (unsigned)j | ((unsigned)d << 16);
    }
}

// ---------------------------------------------------------------------------
// Kernel 2: DTM, transposed — one WAVE (block) per pixel, one lane per image.
// Table entries wave-uniform; weight fetch one coalesced 256B load; per-lane
// serial cum (exact reference cumsum order). Early exit at bound2.
// ---------------------------------------------------------------------------
__global__ void __launch_bounds__(64) dtm_kernel(const unsigned int* __restrict__ TPK,
                                                 const float* __restrict__ xT,
                                                 const float* __restrict__ sums,
                                                 float* __restrict__ F) {
    int lane = threadIdx.x;
    int i = blockIdx.x;
    float s = sums[lane];
    float bound1 = 0.05f * s, bound2 = 0.2f * s;
    const unsigned int* tp = TPK + (size_t)i * NPIX;
    float cum = 0.f, acc1 = 0.f, acc2 = 0.f;
    for (int t0 = 0; t0 < NPIX; t0 += 8) {   // 784 % 8 == 0
        unsigned int e[8];
        #pragma unroll
        for (int u = 0; u < 8; ++u) e[u] = tp[t0 + u];     // wave-uniform
        float w[8];
        #pragma unroll
        for (int u = 0; u < 8; ++u) w[u] = xT[(e[u] & 0xffffu) * NIMG + lane];
        #pragma unroll
        for (int u = 0; u < 8; ++u) {
            float d2 = (float)(e[u] >> 16);
            float ce = cum;
            cum += w[u];
            acc1 += fminf(fmaxf(bound1 - ce, 0.f), w[u]) * d2;
            acc2 += fminf(fmaxf(bound2 - ce, 0.f), w[u]) * d2;
        }
        if (__ballot(cum < bound2) == 0ull) break;  // all lanes done
    }
    F[0 * NIMG * NPIX + lane * NPIX + i] = sqrtf(acc1 / bound1);
    F[1 * NIMG * NPIX + lane * NPIX + i] = sqrtf(acc2 / bound2);
}

// ---------------------------------------------------------------------------
// Kernel 3: fused RANK + UF (basin decomposition) + LANDSCAPE.
// 1024 threads (4 waves/SIMD). Rank now uses PRECOMPUTED packed u64 keys in
// LDS (no per-iteration repack; v_cmp_lt_u64 directly) and skips inactive
// waves. Landscape reads pairsI/fv directly (LDS broadcast) — no staging.
// ---------------------------------------------------------------------------
template<int NN>   // NN = 4 (dir 0) or 8 (dir 1)
__device__ int uf_basin_run(const int* posA, const int* ordA,
                            int* bas, unsigned int* pb, int* comp,
                            int* recs, int* pairsI,
                            int2* mergeLDS, int* shInts, int* wtot16) {
    const int tid = threadIdx.x;
    const int lane = tid & 63, wv = tid >> 6;   // wv in [0,16)

    // ---- P2: steepest-descent forest ----
    for (int s = tid; s < NPIX; s += 1024) {
        int si = s / HW, sj = s % HW;
        int bestPos = posA[s], best = s;
        #pragma unroll
        for (int o = 0; o < NN; ++o) {
            int dx = ((DXPK >> (2 * o)) & 3) - 1;
            int dy = ((DYPK >> (2 * o)) & 3) - 1;
            int ui = si + dx, uj = sj + dy;
            if ((unsigned)ui < (unsigned)HW && (unsigned)uj < (unsigned)HW) {
                int u = ui * HW + uj;
                int pu = posA[u];
                if (pu < bestPos) { bestPos = pu; best = u; }
            }
        }
        bas[s] = best;
    }
    __syncthreads();

    // ---- P3: pointer jumping with convergence early-exit ----
    for (int it = 0; it < 10; ++it) {
        int changed = 0;
        for (int s = tid; s < NPIX; s += 1024) {
            int b = bas[s];
            int bb = bas[b];
            if (bb != b) { bas[s] = bb; changed = 1; }
        }
        if (__syncthreads_count(changed) == 0) break;
    }

    // ---- pack (pos<<10 | bas) for single-gather P4 ----
    for (int s = tid; s < NPIX; s += 1024)
        pb[s] = ((unsigned)posA[s] << 10) | (unsigned)bas[s];
    __syncthreads();

    // ---- P4: candidate records in rank order (single pass, r = tid) ----
    int nrec = 0;
    {
        int r = tid;
        int cnt = 0;
        int myr[NN - 1];
        int got[NN - 1];
        #pragma unroll
        for (int t = 0; t < NN - 1; ++t) { got[t] = -1; myr[t] = 0; }
        if (r > 0 && r < NPIX) {
            int v = ordA[r];
            int vi = v / HW, vj = v % HW;
            int pivot = (int)(pb[v] & 1023u);
            #pragma unroll
            for (int o = 0; o < NN; ++o) {
                int dx = ((DXPK >> (2 * o)) & 3) - 1;
                int dy = ((DYPK >> (2 * o)) & 3) - 1;
                int ui = vi + dx, uj = vj + dy;
                if ((unsigned)ui < (unsigned)HW && (unsigned)uj < (unsigned)HW) {
                    int u = ui * HW + uj;
                    unsigned e = pb[u];
                    if ((int)(e >> 10) < r) {
                        int b = (int)(e & 1023u);
                        bool dup = (b == pivot);
                        #pragma unroll
                        for (int t = 0; t < NN - 1; ++t) dup = dup || (got[t] == b);
                        if (!dup) {
                            #pragma unroll
                            for (int t = 0; t < NN - 1; ++t)
                                if (t == cnt) { got[t] = b; myr[t] = (v << 20) | (pivot << 10) | b; }
                            cnt++;
                        }
                    }
                }
            }
        }
        // block-wide exclusive prefix of cnt (16 wave partials)
        int p = cnt;
        for (int off = 1; off < 64; off <<= 1) {
            int t2 = __shfl_up(p, off, 64);
            if (lane >= off) p += t2;
        }
        if (lane == 63) wtot16[wv] = p;
        __syncthreads();
        int wadd = 0;
        for (int w2 = 0; w2 < wv; ++w2) wadd += wtot16[w2];
        int tot = 0;
        #pragma unroll
        for (int w2 = 0; w2 < 16; ++w2) tot += wtot16[w2];
        int excl = wadd + p - cnt;
        #pragma unroll
        for (int t = 0; t < NN - 1; ++t)
            if (t < cnt) recs[excl + t] = myr[t];
        nrec = tot;
        __syncthreads();
    }

    // ---- P5: ballot-driven serial UF (wave 0), block-wide flatten ----
    int k = 0;
    for (int base = 0; base < nrec; base += 64) {
        int nrem = 0;
        if (wv == 0) {
            int idx = base + lane;
            int rec = (idx < nrec) ? recs[idx] : 0;
            int pa = (rec >> 10) & 1023, pbn = rec & 1023;
            int ka = 0, kb = 0;
            if (idx < nrec) { ka = comp[pa]; kb = comp[pbn]; }
            for (;;) {
                unsigned long long d = __ballot(ka != kb);
                if (d == 0ull) break;
                int i = (int)__ffsll((long long)d) - 1;   // lowest lane = lowest rank
                int sA = __builtin_amdgcn_readlane(ka, i);
                int sB = __builtin_amdgcn_readlane(kb, i);
                int w = min(sA, sB), l = max(sA, sB);     // uniform scalars
                int sv = __builtin_amdgcn_readlane(rec, i) >> 20;
                if (lane == 0) {
                    pairsI[k] = (l & 1023) | (sv << 10);
                    mergeLDS[nrem] = make_int2(l, w);
                }
                k++;
                ka = (ka == l) ? w : ka;
                kb = (kb == l) ? w : kb;
                nrem++;
                if (nrem == 63) {              // overflow guard (rare): wave-0 flatten
                    for (int s = lane; s < NPIX; s += 64) {
                        int cv = comp[s], c0 = cv;
                        for (int e = 0; e < nrem; ++e) {
                            int2 me = mergeLDS[e];
                            cv = (cv == me.x) ? me.y : cv;
                        }
                        if (cv != c0) comp[s] = cv;
                    }
                    if (idx < nrec) { ka = comp[pa]; kb = comp[pbn]; }
                    nrem = 0;
                }
            }
            if (lane == 0) shInts[0] = nrem;
        }
        __syncthreads();
        int nr = shInts[0];
        if (nr > 0) {                          // flatten with all 1024 threads
            for (int s = tid; s < NPIX; s += 1024) {
                int cv = comp[s], c0 = cv;
                for (int e = 0; e < nr; ++e) {
                    int2 me = mergeLDS[e];
                    cv = (cv == me.x) ? me.y : cv;
                }
                if (cv != c0) comp[s] = cv;
            }
        }
        __syncthreads();
    }
    if (tid == 0) shInts[1] = k;
    __syncthreads();
    return shInts[1];
}

__global__ void __launch_bounds__(1024) uf_land_kernel(const float* __restrict__ F,
                                                       float* __restrict__ LAM1,
                                                       float* __restrict__ LAM2) {
    __shared__ int posA[NPIX], ordA[NPIX], bas[NPIX], comp[NPIX], pairsI[NPIX];
    __shared__ unsigned int pbArr[NPIX];  // packed (pos,bas) for P4
    __shared__ alignas(16) unsigned long long key64[NPIX];  // rank keys
    __shared__ float fv[NPIX];
    __shared__ int recs[MAXREC];
    __shared__ int2 mergeLDS[64];
    __shared__ int shInts[2];
    __shared__ int wtot16[16];
    int tid = threadIdx.x;
    int task = blockIdx.x;
    int feat = task >> 7;
    int dir = (task >> 6) & 1;
    int m = task & 63;
    const float* fr = F + feat * NIMG * NPIX + m * NPIX;

    // load values + precomputed packed u64 sort keys (values >= 0: bits
    // monotone; dir==1 uses ~bits so both dirs are the same ascending cmp)
    for (int j = tid; j < NPIX; j += 1024) {
        float f = fr[j];
        fv[j] = f;
        unsigned int b = __float_as_uint(f);
        if (dir) b = ~b;
        key64[j] = ((unsigned long long)b << 10) | (unsigned)j;
    }
    __syncthreads();

    // ---- fused rank: b128 reads of prepacked u64 keys, 1 cmp each ----
    if (tid < NPIX) {
        unsigned long long pki = key64[tid];
        int rank = 0;
        const ulonglong2* k2 = (const ulonglong2*)key64;
        for (int c = 0; c < NPIX / 2; ++c) {
            ulonglong2 kv = k2[c];
            rank += (int)(kv.x < pki) + (int)(kv.y < pki);
        }
        posA[tid] = rank;
        ordA[rank] = tid;
    }
    __syncthreads();
    for (int s = tid; s < NPIX; s += 1024) comp[s] = (posA[s] << 10) | s;
    // (comp init needs no barrier before P2: P2 reads only posA)

    int k;
    if (dir == 0) k = uf_basin_run<4>(posA, ordA, bas, pbArr, comp, recs, pairsI,
                                      mergeLDS, shInts, wtot16);
    else          k = uf_basin_run<8>(posA, ordA, bas, pbArr, comp, recs, pairsI,
                                      mergeLDS, shInts, wtot16);

    // ---- fused landscape: top-3 tents directly from pairsI (broadcast) ----
    if (tid < 32) {
        int t = tid;
        float start = (feat == 0) ? 0.f : 1.f;
        float end   = (feat == 0) ? 7.f : 8.f;
        float tv = start + (end - start) * ((float)t / 31.f);
        float v0 = 0.f, v1 = 0.f, v2 = 0.f;
        for (int p = 0; p < k; ++p) {
            int pi = pairsI[p];                   // same addr all lanes
            float fb = fv[pi & 1023], fd = fv[pi >> 10];
            float bb = dir ? fd : fb;
            float dd = dir ? fb : fd;
            float tent = fmaxf(fminf(tv - bb, dd - tv), 0.f);
            if (tent > v0)      { v2 = v1; v1 = v0; v0 = tent; }
            else if (tent > v1) { v2 = v1; v1 = tent; }
            else if (tent > v2) { v2 = tent; }
        }
        if (feat == 0) {
            float* lam = LAM1 + m * 128 + dir * 64;
            lam[0 * 32 + t] = v0;
            lam[1 * 32 + t] = v1;
        } else {
            float* lam = LAM2 + m * 192 + dir * 96;
            lam[0 * 32 + t] = v0;
            lam[1 * 32 + t] = v1;
            lam[2 * 32 + t] = v2;
        }
    }
}

// ---------------------------------------------------------------------------
// Kernel 4: MLP head. One block (64 threads) per image.
// ---------------------------------------------------------------------------
__global__ void mlp_kernel(const float* __restrict__ LAM1, const float* __restrict__ LAM2,
                           const float* __restrict__ w1, const float* __restrict__ b1,
                           const float* __restrict__ w2, const float* __restrict__ b2,
                           const float* __restrict__ wf, const float* __restrict__ bf,
                           float* __restrict__ out) {
    __shared__ float xc[64];
    int m = blockIdx.x;
    int n = threadIdx.x;
    if (n < 32) {
        float acc = b1[n];
        const float* l = LAM1 + m * 128;
        for (int c = 0; c < 128; ++c) acc += w1[n * 128 + c] * l[c];
        xc[n] = fmaxf(acc, 0.f);
    } else {
        int n2 = n - 32;
        float acc = b2[n2];
        const float* l = LAM2 + m * 192;
        for (int c = 0; c < 192; ++c) acc += w2[n2 * 192 + c] * l[c];
        xc[n] = fmaxf(acc, 0.f);
    }
    __syncthreads();
    if (n < 10) {
        float acc = bf[n];
        for (int c = 0; c < 64; ++c) acc += wf[n * 64 + c] * xc[c];
        out[m * 10 + n] = acc;
    }
}

extern "C" void kernel_launch(void* const* d_in, const int* in_sizes, int n_in,
                              void* d_out, int out_size, void* d_ws, size_t ws_size,
                              hipStream_t stream) {
    const float* x  = (const float*)d_in[0];
    const float* w1 = (const float*)d_in[1];
    const float* b1 = (const float*)d_in[2];
    const float* w2 = (const float*)d_in[3];
    const float* b2 = (const float*)d_in[4];
    const float* wf = (const float*)d_in[5];
    const float* bf = (const float*)d_in[6];
    float* out = (float*)d_out;

    char* ws = (char*)d_ws;
    size_t off = 0;
    unsigned int* TPK = (unsigned int*)(ws + off); off += (size_t)NPIX * NPIX * 4;
    float* XT   = (float*)(ws + off); off += (size_t)NPIX * NIMG * 4;
    float* SUMS = (float*)(ws + off); off += 256;
    float* F    = (float*)(ws + off); off += (size_t)2 * NIMG * NPIX * 4;
    float* LAM1 = (float*)(ws + off); off += (size_t)NIMG * 128 * 4;
    float* LAM2 = (float*)(ws + off); off += (size_t)NIMG * 192 * 4;

    consts_sums_kernel<<<NPIX + NIMG, 256, 0, stream>>>(TPK, x, SUMS, XT);
    dtm_kernel<<<NPIX, 64, 0, stream>>>(TPK, XT, SUMS, F);
    uf_land_kernel<<<256, 1024, 0, stream>>>(F, LAM1, LAM2);
    mlp_kernel<<<NIMG, 64, 0, stream>>>(LAM1, LAM2, w1, b1, w2, b2, wf, bf, out);
}